// Round 1
// baseline (8317.366 us; speedup 1.0000x reference)
//
#include <hip/hip_runtime.h>
#include <cfloat>

#define N_PTS 2048
#define BATCH 8
#define KNN_K 20
#define XC_CH 512

constexpr float BN_SCALE_F = 0.9999950000374997f; // 1/sqrt(1+1e-5)

// ---------------------------------------------------------------- sqnorm
__global__ void sqnorm_kernel(const float* __restrict__ in, int stride, int C,
                              float* __restrict__ xx) {
  int i = blockIdx.x * blockDim.x + threadIdx.x;
  if (i >= BATCH * N_PTS) return;
  const float* row = in + (size_t)i * stride;
  float s = 0.f;
  for (int c = 0; c < C; ++c) { float v = row[c]; s += v * v; }
  xx[i] = s;
}

// ---------------------------------------------------------------- knn top-20
// One block handles R=4 query rows of one batch. Distances in LDS, then 20
// rounds of block-argmax with min-index tie-break (matches jax.lax.top_k).
template<int C>
__global__ void knn_kernel(const float* __restrict__ in, int stride,
                           const float* __restrict__ xx,
                           int* __restrict__ knn_out) {
  constexpr int R = 4;
  constexpr int MT = N_PTS / 256;            // 8 points per thread
  constexpr int CT = (C % 16 == 0) ? 16 : C; // c-tile kept in registers
  int b  = blockIdx.x / (N_PTS / R);
  int ng = blockIdx.x % (N_PTS / R);
  int n0 = ng * R;
  int tid = threadIdx.x;

  __shared__ __align__(16) float ctr[R][C];
  __shared__ float dist[R][N_PTS];
  __shared__ float rv[256];
  __shared__ int   ri[256];

  for (int e = tid; e < R * C; e += 256) {
    int r = e / C, c = e % C;
    ctr[r][c] = in[(size_t)(b * N_PTS + n0 + r) * stride + c];
  }
  __syncthreads();

  float xxn[R];
#pragma unroll
  for (int r = 0; r < R; ++r) xxn[r] = xx[b * N_PTS + n0 + r];

  float acc[MT][R];
#pragma unroll
  for (int mi = 0; mi < MT; ++mi)
#pragma unroll
    for (int r = 0; r < R; ++r) acc[mi][r] = 0.f;

  for (int c0 = 0; c0 < C; c0 += CT) {
    float cr[R][CT];
#pragma unroll
    for (int r = 0; r < R; ++r)
#pragma unroll
      for (int q = 0; q < CT; ++q) cr[r][q] = ctr[r][c0 + q];
#pragma unroll
    for (int mi = 0; mi < MT; ++mi) {
      int m = tid + mi * 256;
      const float* row = in + (size_t)(b * N_PTS + m) * stride + c0;
      float rvv[CT];
      if constexpr (CT % 4 == 0) {
#pragma unroll
        for (int q = 0; q < CT; q += 4) {
          float4 t = *(const float4*)&row[q];
          rvv[q] = t.x; rvv[q + 1] = t.y; rvv[q + 2] = t.z; rvv[q + 3] = t.w;
        }
      } else {
#pragma unroll
        for (int q = 0; q < CT; ++q) rvv[q] = row[q];
      }
#pragma unroll
      for (int q = 0; q < CT; ++q)
#pragma unroll
        for (int r = 0; r < R; ++r) acc[mi][r] += rvv[q] * cr[r][q];
    }
  }
#pragma unroll
  for (int mi = 0; mi < MT; ++mi) {
    int m = tid + mi * 256;
    float xm = xx[b * N_PTS + m];
#pragma unroll
    for (int r = 0; r < R; ++r)
      dist[r][m] = 2.f * acc[mi][r] - xxn[r] - xm;
  }
  __syncthreads();

  for (int r = 0; r < R; ++r) {
    for (int sel = 0; sel < KNN_K; ++sel) {
      float bv = -FLT_MAX; int bi = N_PTS;
      for (int m = tid; m < N_PTS; m += 256) {
        float v = dist[r][m];
        if (v > bv) { bv = v; bi = m; }   // ascending m: first max kept
      }
      rv[tid] = bv; ri[tid] = bi;
      __syncthreads();
#pragma unroll
      for (int s = 128; s > 0; s >>= 1) {
        if (tid < s) {
          float v2 = rv[tid + s]; int i2 = ri[tid + s];
          if (v2 > rv[tid] || (v2 == rv[tid] && i2 < ri[tid])) {
            rv[tid] = v2; ri[tid] = i2;
          }
        }
        __syncthreads();
      }
      if (tid == 0) {
        knn_out[(size_t)(b * N_PTS + n0 + r) * KNN_K + sel] = ri[0];
        dist[r][ri[0]] = -FLT_MAX;
      }
      __syncthreads();
    }
  }
}

// ---------------------------------------------------------------- edge conv
// One block per (b,n). feat[k][0:C]=nbr-ctr, [C:2C]=ctr staged in LDS, then a
// register-tiled TKxTO micro-GEMM against W (OxC2), bn+lrelu, max over k.
template<int C, int O, int TO, int TK>
__global__ void edgeconv_kernel(const float* __restrict__ in, int in_stride,
                                const int* __restrict__ knn_idx,
                                const float* __restrict__ W,
                                const float* __restrict__ gamma,
                                const float* __restrict__ beta,
                                float* __restrict__ out, int out_stride) {
  constexpr int C2 = 2 * C;
  constexpr int KG = KNN_K / TK;   // 4
  constexpr int OT = O / TO;
  constexpr int BLOCK = KG * OT;
  constexpr int FPAD = C2 + 4;
  int bn = blockIdx.x;
  int b = bn / N_PTS;
  int tid = threadIdx.x;

  __shared__ __align__(16) float ctr[C];
  __shared__ __align__(16) float feat[KNN_K][FPAD];
  __shared__ float red[KG][O];

  for (int c = tid; c < C; c += BLOCK)
    ctr[c] = in[(size_t)bn * in_stride + c];
  __syncthreads();

  for (int e = tid; e < KNN_K * C; e += BLOCK) {
    int k = e / C, c = e % C;
    int m = knn_idx[(size_t)bn * KNN_K + k];
    float nb = in[(size_t)(b * N_PTS + m) * in_stride + c];
    float cv = ctr[c];
    feat[k][c]     = nb - cv;
    feat[k][C + c] = cv;
  }
  __syncthreads();

  int og = tid % OT, kg = tid / OT;
  int o0 = og * TO, k0 = kg * TK;

  float acc[TK][TO];
#pragma unroll
  for (int i = 0; i < TK; ++i)
#pragma unroll
    for (int j = 0; j < TO; ++j) acc[i][j] = 0.f;

  if constexpr (C2 % 4 == 0) {
    for (int c = 0; c < C2; c += 4) {
      float4 f[TK];
#pragma unroll
      for (int i = 0; i < TK; ++i) f[i] = *(const float4*)&feat[k0 + i][c];
#pragma unroll
      for (int j = 0; j < TO; ++j) {
        float4 w = *(const float4*)&W[(size_t)(o0 + j) * C2 + c];
#pragma unroll
        for (int i = 0; i < TK; ++i)
          acc[i][j] += f[i].x * w.x + f[i].y * w.y + f[i].z * w.z + f[i].w * w.w;
      }
    }
  } else {
    for (int c = 0; c < C2; ++c) {
      float fv[TK];
#pragma unroll
      for (int i = 0; i < TK; ++i) fv[i] = feat[k0 + i][c];
#pragma unroll
      for (int j = 0; j < TO; ++j) {
        float w = W[(size_t)(o0 + j) * C2 + c];
#pragma unroll
        for (int i = 0; i < TK; ++i) acc[i][j] += fv[i] * w;
      }
    }
  }

#pragma unroll
  for (int j = 0; j < TO; ++j) {
    float g = gamma[o0 + j], be = beta[o0 + j];
    float mx = -FLT_MAX;
#pragma unroll
    for (int i = 0; i < TK; ++i) {
      float y = g * (acc[i][j] * BN_SCALE_F) + be;
      y = (y > 0.f) ? y : 0.2f * y;
      mx = fmaxf(mx, y);
    }
    red[kg][o0 + j] = mx;
  }
  __syncthreads();

  for (int o = tid; o < O; o += BLOCK) {
    float mx = red[0][o];
#pragma unroll
    for (int g2 = 1; g2 < KG; ++g2) mx = fmaxf(mx, red[g2][o]);
    out[(size_t)bn * out_stride + o] = mx;
  }
}

// ---------------------------------------------------------------- W5 GEMM + fused max/sum pooling partials
__global__ void gemm_w5_kernel(const float* __restrict__ xc,
                               const float* __restrict__ W5,
                               const float* __restrict__ g5,
                               const float* __restrict__ b5,
                               float* __restrict__ pmax,
                               float* __restrict__ psum) {
  constexpr int TO = 8, TN = 4, CHUNK = 64, NCH = N_PTS / CHUNK; // 32 chunks
  int b  = blockIdx.x / NCH;
  int ch = blockIdx.x % NCH;
  int n0 = ch * CHUNK;
  int tid = threadIdx.x;       // 128 threads -> 1024 outputs
  int o0 = tid * TO;

  __shared__ __align__(16) float rows[TN][XC_CH];

  float mxv[TO], smv[TO];
#pragma unroll
  for (int j = 0; j < TO; ++j) { mxv[j] = -FLT_MAX; smv[j] = 0.f; }

  for (int nn = 0; nn < CHUNK; nn += TN) {
    __syncthreads();
    for (int e = tid; e < TN * XC_CH; e += 128) {
      int i = e / XC_CH, c = e % XC_CH;
      rows[i][c] = xc[(size_t)(b * N_PTS + n0 + nn + i) * XC_CH + c];
    }
    __syncthreads();

    float acc[TN][TO];
#pragma unroll
    for (int i = 0; i < TN; ++i)
#pragma unroll
      for (int j = 0; j < TO; ++j) acc[i][j] = 0.f;

    for (int c = 0; c < XC_CH; c += 4) {
      float4 f[TN];
#pragma unroll
      for (int i = 0; i < TN; ++i) f[i] = *(const float4*)&rows[i][c];
#pragma unroll
      for (int j = 0; j < TO; ++j) {
        float4 w = *(const float4*)&W5[(size_t)(o0 + j) * XC_CH + c];
#pragma unroll
        for (int i = 0; i < TN; ++i)
          acc[i][j] += f[i].x * w.x + f[i].y * w.y + f[i].z * w.z + f[i].w * w.w;
      }
    }
#pragma unroll
    for (int j = 0; j < TO; ++j) {
      float g = g5[o0 + j], be = b5[o0 + j];
#pragma unroll
      for (int i = 0; i < TN; ++i) {
        float y = g * (acc[i][j] * BN_SCALE_F) + be;
        y = (y > 0.f) ? y : 0.2f * y;
        mxv[j] = fmaxf(mxv[j], y);
        smv[j] += y;
      }
    }
  }
#pragma unroll
  for (int j = 0; j < TO; ++j) {
    size_t o = (size_t)(b * NCH + ch) * 1024 + o0 + j;
    pmax[o] = mxv[j];
    psum[o] = smv[j];
  }
}

// ---------------------------------------------------------------- pooled-feature FC head
__global__ void head_kernel(const float* __restrict__ pmax,
                            const float* __restrict__ psum,
                            const float* __restrict__ L1,
                            const float* __restrict__ g6, const float* __restrict__ b6,
                            const float* __restrict__ L2, const float* __restrict__ L2b,
                            const float* __restrict__ g7, const float* __restrict__ b7,
                            const float* __restrict__ L3, const float* __restrict__ L3b,
                            float* __restrict__ out) {
  constexpr int NCH = 32;
  int b = blockIdx.x;
  int tid = threadIdx.x;
  __shared__ float gvec[2048];
  __shared__ float h1[512];
  __shared__ float h2[256];

  for (int o = tid; o < 1024; o += 256) {
    float mx = -FLT_MAX, sm = 0.f;
    for (int ch = 0; ch < NCH; ++ch) {
      size_t idx = (size_t)(b * NCH + ch) * 1024 + o;
      mx = fmaxf(mx, pmax[idx]);
      sm += psum[idx];
    }
    gvec[o] = mx;                       // hmax
    gvec[1024 + o] = sm * (1.f / 2048.f); // havg
  }
  __syncthreads();
  for (int o = tid; o < 512; o += 256) {
    const float* w = &L1[(size_t)o * 2048];
    float s = 0.f;
    for (int c = 0; c < 2048; ++c) s += w[c] * gvec[c];
    float y = g6[o] * (s * BN_SCALE_F) + b6[o];
    h1[o] = (y > 0.f) ? y : 0.2f * y;
  }
  __syncthreads();
  if (tid < 256) {
    const float* w = &L2[(size_t)tid * 512];
    float s = L2b[tid];
    for (int c = 0; c < 512; ++c) s += w[c] * h1[c];
    float y = g7[tid] * (s * BN_SCALE_F) + b7[tid];
    h2[tid] = (y > 0.f) ? y : 0.2f * y;
  }
  __syncthreads();
  if (tid < 10) {
    const float* w = &L3[(size_t)tid * 256];
    float s = L3b[tid];
    for (int c = 0; c < 256; ++c) s += w[c] * h2[c];
    out[b * 10 + tid] = s;
  }
}

// ---------------------------------------------------------------- launch
extern "C" void kernel_launch(void* const* d_in, const int* in_sizes, int n_in,
                              void* d_out, int out_size, void* d_ws, size_t ws_size,
                              hipStream_t stream) {
  const float* x   = (const float*)d_in[0];
  const float* W1  = (const float*)d_in[1];
  const float* g1  = (const float*)d_in[2];
  const float* b1  = (const float*)d_in[3];
  const float* W2  = (const float*)d_in[4];
  const float* g2  = (const float*)d_in[5];
  const float* b2  = (const float*)d_in[6];
  const float* W3  = (const float*)d_in[7];
  const float* g3  = (const float*)d_in[8];
  const float* b3  = (const float*)d_in[9];
  const float* W4  = (const float*)d_in[10];
  const float* g4  = (const float*)d_in[11];
  const float* b4  = (const float*)d_in[12];
  const float* W5  = (const float*)d_in[13];
  const float* g5  = (const float*)d_in[14];
  const float* b5  = (const float*)d_in[15];
  const float* L1  = (const float*)d_in[16];
  const float* g6  = (const float*)d_in[17];
  const float* b6  = (const float*)d_in[18];
  const float* L2  = (const float*)d_in[19];
  const float* L2b = (const float*)d_in[20];
  const float* g7  = (const float*)d_in[21];
  const float* b7  = (const float*)d_in[22];
  const float* L3  = (const float*)d_in[23];
  const float* L3b = (const float*)d_in[24];
  float* out = (float*)d_out;

  // workspace layout (~37 MB)
  float* xc   = (float*)d_ws;                              // 8*2048*512
  float* xx   = xc + (size_t)BATCH * N_PTS * XC_CH;        // 8*2048
  int*   idx  = (int*)(xx + BATCH * N_PTS);                // 8*2048*20
  float* pmax = (float*)(idx + (size_t)BATCH * N_PTS * KNN_K); // 8*32*1024
  float* psum = pmax + (size_t)BATCH * 32 * 1024;

  int sq_blocks = (BATCH * N_PTS + 255) / 256;   // 64
  int knn_blocks = BATCH * (N_PTS / 4);          // 4096
  int ec_blocks = BATCH * N_PTS;                 // 16384

  // layer 1: x(C=3) -> xc[:, 0:64]
  sqnorm_kernel<<<sq_blocks, 256, 0, stream>>>(x, 3, 3, xx);
  knn_kernel<3><<<knn_blocks, 256, 0, stream>>>(x, 3, xx, idx);
  edgeconv_kernel<3, 64, 4, 5><<<ec_blocks, 64, 0, stream>>>(
      x, 3, idx, W1, g1, b1, xc + 0, XC_CH);
  // layer 2: x1(C=64) -> xc[:, 64:128]
  sqnorm_kernel<<<sq_blocks, 256, 0, stream>>>(xc + 0, XC_CH, 64, xx);
  knn_kernel<64><<<knn_blocks, 256, 0, stream>>>(xc + 0, XC_CH, xx, idx);
  edgeconv_kernel<64, 64, 4, 5><<<ec_blocks, 64, 0, stream>>>(
      xc + 0, XC_CH, idx, W2, g2, b2, xc + 64, XC_CH);
  // layer 3: x2(C=64) -> xc[:, 128:256]
  sqnorm_kernel<<<sq_blocks, 256, 0, stream>>>(xc + 64, XC_CH, 64, xx);
  knn_kernel<64><<<knn_blocks, 256, 0, stream>>>(xc + 64, XC_CH, xx, idx);
  edgeconv_kernel<64, 128, 8, 5><<<ec_blocks, 64, 0, stream>>>(
      xc + 64, XC_CH, idx, W3, g3, b3, xc + 128, XC_CH);
  // layer 4: x3(C=128) -> xc[:, 256:512]
  sqnorm_kernel<<<sq_blocks, 256, 0, stream>>>(xc + 128, XC_CH, 128, xx);
  knn_kernel<128><<<knn_blocks, 256, 0, stream>>>(xc + 128, XC_CH, xx, idx);
  edgeconv_kernel<128, 256, 8, 5><<<ec_blocks, 128, 0, stream>>>(
      xc + 128, XC_CH, idx, W4, g4, b4, xc + 256, XC_CH);

  // W5 GEMM + pooling partials, then FC head
  gemm_w5_kernel<<<BATCH * 32, 128, 0, stream>>>(xc, W5, g5, b5, pmax, psum);
  head_kernel<<<BATCH, 256, 0, stream>>>(pmax, psum, L1, g6, b6,
                                         L2, L2b, g7, b7, L3, L3b, out);
}

// Round 2
// 2853.208 us; speedup vs baseline: 2.9151x; 2.9151x over previous
//
#include <hip/hip_runtime.h>
#include <cfloat>

#define N_PTS 2048
#define BATCH 8
#define KNN_K 20
#define XC_CH 512

constexpr float BN_SCALE_F = 0.9999950000374997f; // 1/sqrt(1+1e-5)

// ---------------------------------------------------------------- sqnorm
__global__ void sqnorm_kernel(const float* __restrict__ in, int stride, int C,
                              float* __restrict__ xx) {
  int i = blockIdx.x * blockDim.x + threadIdx.x;
  if (i >= BATCH * N_PTS) return;
  const float* row = in + (size_t)i * stride;
  float s = 0.f;
  for (int c = 0; c < C; ++c) { float v = row[c]; s += v * v; }
  xx[i] = s;
}

// ---------------------------------------------------------------- knn top-20
// One block = 4 query rows of one batch. Distances computed into LDS with a
// register-tiled inner product, then each WAVE owns one row: 2048 dists pulled
// into 32 regs/lane, 20 rounds of (local scan + shfl_xor butterfly argmax)
// with min-index tie-break. No __syncthreads in the selection loop.
template<int C>
__global__ void knn_kernel(const float* __restrict__ in, int stride,
                           const float* __restrict__ xx,
                           int* __restrict__ knn_out) {
  constexpr int R = 4;
  constexpr int MT = N_PTS / 256;            // 8 points per thread
  constexpr int CT = (C % 16 == 0) ? 16 : C; // c-tile kept in registers
  int b  = blockIdx.x / (N_PTS / R);
  int ng = blockIdx.x % (N_PTS / R);
  int n0 = ng * R;
  int tid = threadIdx.x;

  __shared__ __align__(16) float ctr[R][C];
  __shared__ float dist[R][N_PTS];

  for (int e = tid; e < R * C; e += 256) {
    int r = e / C, c = e % C;
    ctr[r][c] = in[(size_t)(b * N_PTS + n0 + r) * stride + c];
  }
  __syncthreads();

  float xxn[R];
#pragma unroll
  for (int r = 0; r < R; ++r) xxn[r] = xx[b * N_PTS + n0 + r];

  float acc[MT][R];
#pragma unroll
  for (int mi = 0; mi < MT; ++mi)
#pragma unroll
    for (int r = 0; r < R; ++r) acc[mi][r] = 0.f;

  for (int c0 = 0; c0 < C; c0 += CT) {
    float cr[R][CT];
#pragma unroll
    for (int r = 0; r < R; ++r)
#pragma unroll
      for (int q = 0; q < CT; ++q) cr[r][q] = ctr[r][c0 + q];
#pragma unroll
    for (int mi = 0; mi < MT; ++mi) {
      int m = tid + mi * 256;
      const float* row = in + (size_t)(b * N_PTS + m) * stride + c0;
      float rvv[CT];
      if constexpr (CT % 4 == 0) {
#pragma unroll
        for (int q = 0; q < CT; q += 4) {
          float4 t = *(const float4*)&row[q];
          rvv[q] = t.x; rvv[q + 1] = t.y; rvv[q + 2] = t.z; rvv[q + 3] = t.w;
        }
      } else {
#pragma unroll
        for (int q = 0; q < CT; ++q) rvv[q] = row[q];
      }
#pragma unroll
      for (int q = 0; q < CT; ++q)
#pragma unroll
        for (int r = 0; r < R; ++r) acc[mi][r] += rvv[q] * cr[r][q];
    }
  }
#pragma unroll
  for (int mi = 0; mi < MT; ++mi) {
    int m = tid + mi * 256;
    float xm = xx[b * N_PTS + m];
#pragma unroll
    for (int r = 0; r < R; ++r)
      dist[r][m] = 2.f * acc[mi][r] - xxn[r] - xm;
  }
  __syncthreads();

  // --- selection: wave w owns row w ---
  int w = tid >> 6;          // 0..3
  int lane = tid & 63;
  float v[32];
#pragma unroll
  for (int i = 0; i < 32; ++i) v[i] = dist[w][i * 64 + lane];

  int out_base = (b * N_PTS + n0 + w) * KNN_K;
  for (int sel = 0; sel < KNN_K; ++sel) {
    float bv = -FLT_MAX; int bi = 0x3fffffff;
#pragma unroll
    for (int i = 0; i < 32; ++i) {
      if (v[i] > bv) { bv = v[i]; bi = i * 64 + lane; }
    }
#pragma unroll
    for (int off = 32; off > 0; off >>= 1) {
      float ov = __shfl_xor(bv, off);
      int   oi = __shfl_xor(bi, off);
      if (ov > bv || (ov == bv && oi < bi)) { bv = ov; bi = oi; }
    }
    if (lane == 0) knn_out[out_base + sel] = bi;
    // invalidate winner
    if ((bi & 63) == lane) {
#pragma unroll
      for (int i = 0; i < 32; ++i)
        if (bi == i * 64 + lane) v[i] = -FLT_MAX;
    }
  }
}

// ---------------------------------------------------------------- W' prep
// Wp[o][c] = W[o][c] for o<O ; Wp[O+o][c] = W[o][C+c] - W[o][c]
__global__ void prep_wp_kernel(const float* __restrict__ W,
                               float* __restrict__ Wp, int O, int C) {
  int t = blockIdx.x * 256 + threadIdx.x;
  if (t >= 2 * O * C) return;
  int o = t / C, c = t % C;
  Wp[t] = (o < O) ? W[(size_t)o * 2 * C + c]
                  : (W[(size_t)(o - O) * 2 * C + C + c] -
                     W[(size_t)(o - O) * 2 * C + c]);
}

// ---------------------------------------------------------------- layer-1 uv (K=3)
__global__ void gemm_uv3_kernel(const float* __restrict__ x,
                                const float* __restrict__ Wp,
                                float* __restrict__ out) {
  int t = blockIdx.x * 256 + threadIdx.x;
  if (t >= BATCH * N_PTS * 128) return;
  int n = t >> 7, o = t & 127;
  const float* xr = x + (size_t)n * 3;
  const float* wr = Wp + (size_t)o * 3;
  out[t] = xr[0] * wr[0] + xr[1] * wr[1] + xr[2] * wr[2];
}

// ---------------------------------------------------------------- tiled uv GEMM
// out[n][o] = sum_c X[n][c+?]*Wp[o][c];  X strided, M=16384, NCOLS=2O, K=C.
// BM=BN=64, BK=16, 256 threads, 4x4 micro-tile.
template<int NCOLS, int K>
__global__ void gemm_uv_kernel(const float* __restrict__ X, int xstride,
                               const float* __restrict__ Wp,
                               float* __restrict__ out) {
  constexpr int BM = 64, BN = 64, BK = 16, PAD = 68;
  constexpr int NT = NCOLS / BN;
  int mt = blockIdx.x / NT;
  int nt = blockIdx.x % NT;
  int n0 = mt * BM, o0 = nt * BN;
  int tid = threadIdx.x;
  int lr = tid >> 2;            // 0..63
  int lc = (tid & 3) * 4;       // 0,4,8,12
  int tx = tid & 15, ty = tid >> 4;

  __shared__ __align__(16) float As[BK][PAD];
  __shared__ __align__(16) float Bs[BK][PAD];

  float acc[4][4];
#pragma unroll
  for (int i = 0; i < 4; ++i)
#pragma unroll
    for (int j = 0; j < 4; ++j) acc[i][j] = 0.f;

  for (int k0 = 0; k0 < K; k0 += BK) {
    float4 a = *(const float4*)&X[(size_t)(n0 + lr) * xstride + k0 + lc];
    float4 bb = *(const float4*)&Wp[(size_t)(o0 + lr) * K + k0 + lc];
    __syncthreads();
    As[lc + 0][lr] = a.x; As[lc + 1][lr] = a.y;
    As[lc + 2][lr] = a.z; As[lc + 3][lr] = a.w;
    Bs[lc + 0][lr] = bb.x; Bs[lc + 1][lr] = bb.y;
    Bs[lc + 2][lr] = bb.z; Bs[lc + 3][lr] = bb.w;
    __syncthreads();
#pragma unroll
    for (int kk = 0; kk < BK; ++kk) {
      float4 av = *(const float4*)&As[kk][ty * 4];
      float4 bv = *(const float4*)&Bs[kk][tx * 4];
      float ar[4] = {av.x, av.y, av.z, av.w};
      float br[4] = {bv.x, bv.y, bv.z, bv.w};
#pragma unroll
      for (int i = 0; i < 4; ++i)
#pragma unroll
        for (int j = 0; j < 4; ++j) acc[i][j] += ar[i] * br[j];
    }
  }
#pragma unroll
  for (int i = 0; i < 4; ++i) {
    float4 o4 = {acc[i][0], acc[i][1], acc[i][2], acc[i][3]};
    *(float4*)&out[(size_t)(n0 + ty * 4 + i) * NCOLS + o0 + tx * 4] = o4;
  }
}

// ---------------------------------------------------------------- edge gather+max
// out[n][o] = max_k lrelu(bn(uv[idx[n,k]][o] + uv[n][O+o]))
template<int O>
__global__ void edge_max_kernel(const float* __restrict__ uv,
                                const int* __restrict__ knn_idx,
                                const float* __restrict__ gamma,
                                const float* __restrict__ beta,
                                float* __restrict__ out, int out_stride) {
  constexpr int P = 256 / O;
  int tid = threadIdx.x;
  int p = tid / O, o = tid % O;
  int n = blockIdx.x * P + p;
  int b = n / N_PTS;
  float v = uv[(size_t)n * (2 * O) + O + o];
  float g = gamma[o], be = beta[o];
  const int* ir = knn_idx + (size_t)n * KNN_K;
  int mk[KNN_K];
#pragma unroll
  for (int k = 0; k < KNN_K; ++k) mk[k] = ir[k];
  float mx = -FLT_MAX;
#pragma unroll
  for (int k = 0; k < KNN_K; ++k) {
    float u = uv[(size_t)(b * N_PTS + mk[k]) * (2 * O) + o];
    float y = g * ((u + v) * BN_SCALE_F) + be;
    y = (y > 0.f) ? y : 0.2f * y;
    mx = fmaxf(mx, y);
  }
  out[(size_t)n * out_stride + o] = mx;
}

// ---------------------------------------------------------------- W5 GEMM + fused bn/lrelu + pooling partials
// M=16384 (points), N=1024, K=512. Same tiling as gemm_uv, epilogue reduces
// max/sum over the block's 64 rows -> pmax/psum[b*32+chunk][1024] slice.
__global__ void gemm_w5_kernel(const float* __restrict__ xc,
                               const float* __restrict__ W5,
                               const float* __restrict__ g5,
                               const float* __restrict__ b5,
                               float* __restrict__ pmax,
                               float* __restrict__ psum) {
  constexpr int BM = 64, BN = 64, BK = 16, PAD = 68;
  constexpr int NT = 1024 / BN;  // 16
  int mt = blockIdx.x / NT;
  int nt = blockIdx.x % NT;
  int n0 = mt * BM, o0 = nt * BN;
  int tid = threadIdx.x;
  int lr = tid >> 2;
  int lc = (tid & 3) * 4;
  int tx = tid & 15, ty = tid >> 4;

  __shared__ __align__(16) float As[BK][PAD];
  __shared__ __align__(16) float Bs[BK][PAD];

  float acc[4][4];
#pragma unroll
  for (int i = 0; i < 4; ++i)
#pragma unroll
    for (int j = 0; j < 4; ++j) acc[i][j] = 0.f;

  for (int k0 = 0; k0 < XC_CH; k0 += BK) {
    float4 a = *(const float4*)&xc[(size_t)(n0 + lr) * XC_CH + k0 + lc];
    float4 bb = *(const float4*)&W5[(size_t)(o0 + lr) * XC_CH + k0 + lc];
    __syncthreads();
    As[lc + 0][lr] = a.x; As[lc + 1][lr] = a.y;
    As[lc + 2][lr] = a.z; As[lc + 3][lr] = a.w;
    Bs[lc + 0][lr] = bb.x; Bs[lc + 1][lr] = bb.y;
    Bs[lc + 2][lr] = bb.z; Bs[lc + 3][lr] = bb.w;
    __syncthreads();
#pragma unroll
    for (int kk = 0; kk < BK; ++kk) {
      float4 av = *(const float4*)&As[kk][ty * 4];
      float4 bv = *(const float4*)&Bs[kk][tx * 4];
      float ar[4] = {av.x, av.y, av.z, av.w};
      float br[4] = {bv.x, bv.y, bv.z, bv.w};
#pragma unroll
      for (int i = 0; i < 4; ++i)
#pragma unroll
        for (int j = 0; j < 4; ++j) acc[i][j] += ar[i] * br[j];
    }
  }
  __syncthreads();
  // bn + lrelu + per-thread reduce over its 4 rows; stash in As(max)/Bs(sum)
  float4 gv = *(const float4*)&g5[o0 + tx * 4];
  float4 bvv = *(const float4*)&b5[o0 + tx * 4];
  float gr[4] = {gv.x, gv.y, gv.z, gv.w};
  float br2[4] = {bvv.x, bvv.y, bvv.z, bvv.w};
#pragma unroll
  for (int j = 0; j < 4; ++j) {
    float m = -FLT_MAX, s = 0.f;
#pragma unroll
    for (int i = 0; i < 4; ++i) {
      float y = gr[j] * (acc[i][j] * BN_SCALE_F) + br2[j];
      y = (y > 0.f) ? y : 0.2f * y;
      m = fmaxf(m, y);
      s += y;
    }
    As[ty][tx * 4 + j] = m;
    Bs[ty][tx * 4 + j] = s;
  }
  __syncthreads();
  if (tid < 64) {
    float m = As[0][tid], s = Bs[0][tid];
#pragma unroll
    for (int i = 1; i < 16; ++i) { m = fmaxf(m, As[i][tid]); s += Bs[i][tid]; }
    int b = n0 / N_PTS, ch = (n0 % N_PTS) / BM;
    size_t off = (size_t)(b * 32 + ch) * 1024 + o0 + tid;
    pmax[off] = m;
    psum[off] = s;
  }
}

// ---------------------------------------------------------------- FC head
__global__ void head_kernel(const float* __restrict__ pmax,
                            const float* __restrict__ psum,
                            const float* __restrict__ L1,
                            const float* __restrict__ g6, const float* __restrict__ b6,
                            const float* __restrict__ L2, const float* __restrict__ L2b,
                            const float* __restrict__ g7, const float* __restrict__ b7,
                            const float* __restrict__ L3, const float* __restrict__ L3b,
                            float* __restrict__ out) {
  constexpr int NCH = 32;
  int b = blockIdx.x;
  int tid = threadIdx.x;
  __shared__ float gvec[2048];
  __shared__ float h1[512];
  __shared__ float h2[256];

  for (int o = tid; o < 1024; o += 256) {
    float mx = -FLT_MAX, sm = 0.f;
    for (int ch = 0; ch < NCH; ++ch) {
      size_t idx = (size_t)(b * NCH + ch) * 1024 + o;
      mx = fmaxf(mx, pmax[idx]);
      sm += psum[idx];
    }
    gvec[o] = mx;
    gvec[1024 + o] = sm * (1.f / 2048.f);
  }
  __syncthreads();
  for (int o = tid; o < 512; o += 256) {
    const float* w = &L1[(size_t)o * 2048];
    float s = 0.f;
    for (int c = 0; c < 2048; ++c) s += w[c] * gvec[c];
    float y = g6[o] * (s * BN_SCALE_F) + b6[o];
    h1[o] = (y > 0.f) ? y : 0.2f * y;
  }
  __syncthreads();
  if (tid < 256) {
    const float* w = &L2[(size_t)tid * 512];
    float s = L2b[tid];
    for (int c = 0; c < 512; ++c) s += w[c] * h1[c];
    float y = g7[tid] * (s * BN_SCALE_F) + b7[tid];
    h2[tid] = (y > 0.f) ? y : 0.2f * y;
  }
  __syncthreads();
  if (tid < 10) {
    const float* w = &L3[(size_t)tid * 256];
    float s = L3b[tid];
    for (int c = 0; c < 256; ++c) s += w[c] * h2[c];
    out[b * 10 + tid] = s;
  }
}

// ---------------------------------------------------------------- launch
extern "C" void kernel_launch(void* const* d_in, const int* in_sizes, int n_in,
                              void* d_out, int out_size, void* d_ws, size_t ws_size,
                              hipStream_t stream) {
  const float* x   = (const float*)d_in[0];
  const float* W1  = (const float*)d_in[1];
  const float* g1  = (const float*)d_in[2];
  const float* b1  = (const float*)d_in[3];
  const float* W2  = (const float*)d_in[4];
  const float* g2  = (const float*)d_in[5];
  const float* b2  = (const float*)d_in[6];
  const float* W3  = (const float*)d_in[7];
  const float* g3  = (const float*)d_in[8];
  const float* b3  = (const float*)d_in[9];
  const float* W4  = (const float*)d_in[10];
  const float* g4  = (const float*)d_in[11];
  const float* b4  = (const float*)d_in[12];
  const float* W5  = (const float*)d_in[13];
  const float* g5  = (const float*)d_in[14];
  const float* b5  = (const float*)d_in[15];
  const float* L1  = (const float*)d_in[16];
  const float* g6  = (const float*)d_in[17];
  const float* b6  = (const float*)d_in[18];
  const float* L2  = (const float*)d_in[19];
  const float* L2b = (const float*)d_in[20];
  const float* g7  = (const float*)d_in[21];
  const float* b7  = (const float*)d_in[22];
  const float* L3  = (const float*)d_in[23];
  const float* L3b = (const float*)d_in[24];
  float* out = (float*)d_out;

  // workspace layout (floats): xc | xx | idx | wp | uv (pmax/psum alias uv)
  float* xc = (float*)d_ws;                               // 8*2048*512
  float* xx = xc + (size_t)BATCH * N_PTS * XC_CH;         // 16384
  int*   idx = (int*)(xx + BATCH * N_PTS);                // 16384*20
  float* wp = (float*)(idx + (size_t)BATCH * N_PTS * KNN_K); // up to 512*128
  float* uv = wp + 512 * 128;                             // 16384*512 max
  float* pmax = uv;                                       // alias (uv dead)
  float* psum = uv + (size_t)BATCH * 32 * 1024;

  const int NPTS_TOT = BATCH * N_PTS;                     // 16384
  int sq_blocks  = (NPTS_TOT + 255) / 256;                // 64
  int knn_blocks = BATCH * (N_PTS / 4);                   // 4096

  // ---- layer 1: x (C=3) -> xc[:, 0:64]
  sqnorm_kernel<<<sq_blocks, 256, 0, stream>>>(x, 3, 3, xx);
  knn_kernel<3><<<knn_blocks, 256, 0, stream>>>(x, 3, xx, idx);
  prep_wp_kernel<<<(2 * 64 * 3 + 255) / 256, 256, 0, stream>>>(W1, wp, 64, 3);
  gemm_uv3_kernel<<<(NPTS_TOT * 128 + 255) / 256, 256, 0, stream>>>(x, wp, uv);
  edge_max_kernel<64><<<NPTS_TOT / 4, 256, 0, stream>>>(uv, idx, g1, b1, xc + 0, XC_CH);

  // ---- layer 2: x1 (C=64) -> xc[:, 64:128]
  sqnorm_kernel<<<sq_blocks, 256, 0, stream>>>(xc + 0, XC_CH, 64, xx);
  knn_kernel<64><<<knn_blocks, 256, 0, stream>>>(xc + 0, XC_CH, xx, idx);
  prep_wp_kernel<<<(2 * 64 * 64 + 255) / 256, 256, 0, stream>>>(W2, wp, 64, 64);
  gemm_uv_kernel<128, 64><<<(NPTS_TOT / 64) * (128 / 64), 256, 0, stream>>>(
      xc + 0, XC_CH, wp, uv);
  edge_max_kernel<64><<<NPTS_TOT / 4, 256, 0, stream>>>(uv, idx, g2, b2, xc + 64, XC_CH);

  // ---- layer 3: x2 (C=64) -> xc[:, 128:256]
  sqnorm_kernel<<<sq_blocks, 256, 0, stream>>>(xc + 64, XC_CH, 64, xx);
  knn_kernel<64><<<knn_blocks, 256, 0, stream>>>(xc + 64, XC_CH, xx, idx);
  prep_wp_kernel<<<(2 * 128 * 64 + 255) / 256, 256, 0, stream>>>(W3, wp, 128, 64);
  gemm_uv_kernel<256, 64><<<(NPTS_TOT / 64) * (256 / 64), 256, 0, stream>>>(
      xc + 64, XC_CH, wp, uv);
  edge_max_kernel<128><<<NPTS_TOT / 2, 256, 0, stream>>>(uv, idx, g3, b3, xc + 128, XC_CH);

  // ---- layer 4: x3 (C=128) -> xc[:, 256:512]
  sqnorm_kernel<<<sq_blocks, 256, 0, stream>>>(xc + 128, XC_CH, 128, xx);
  knn_kernel<128><<<knn_blocks, 256, 0, stream>>>(xc + 128, XC_CH, xx, idx);
  prep_wp_kernel<<<(2 * 256 * 128 + 255) / 256, 256, 0, stream>>>(W4, wp, 256, 128);
  gemm_uv_kernel<512, 128><<<(NPTS_TOT / 64) * (512 / 64), 256, 0, stream>>>(
      xc + 128, XC_CH, wp, uv);
  edge_max_kernel<256><<<NPTS_TOT, 256, 0, stream>>>(uv, idx, g4, b4, xc + 256, XC_CH);

  // ---- W5 GEMM + pooling partials, then FC head
  gemm_w5_kernel<<<(NPTS_TOT / 64) * 16, 256, 0, stream>>>(xc, W5, g5, b5, pmax, psum);
  head_kernel<<<BATCH, 256, 0, stream>>>(pmax, psum, L1, g6, b6,
                                         L2, L2b, g7, b7, L3, L3b, out);
}

// Round 3
// 1382.497 us; speedup vs baseline: 6.0162x; 2.0638x over previous
//
#include <hip/hip_runtime.h>
#include <cfloat>

#define N_PTS 2048
#define BATCH 8
#define KNN_K 20
#define XC_CH 512

constexpr float BN_SCALE_F = 0.9999950000374997f; // 1/sqrt(1+1e-5)

// ---------------------------------------------------------------- sqnorm
__global__ void sqnorm_kernel(const float* __restrict__ in, int stride, int C,
                              float* __restrict__ xx) {
  int i = blockIdx.x * blockDim.x + threadIdx.x;
  if (i >= BATCH * N_PTS) return;
  const float* row = in + (size_t)i * stride;
  float s = 0.f;
  for (int c = 0; c < C; ++c) { float v = row[c]; s += v * v; }
  xx[i] = s;
}

// ---------------------------------------------------------------- distance GEMM (C=3)
// D[b_local][i][j] = 2*x_i.x_j - xx_i - xx_j ; 64x64 tile per block.
__global__ void dist3_kernel(const float* __restrict__ X,
                             const float* __restrict__ xx, int b0,
                             float* __restrict__ D) {
  int bl = blockIdx.x;
  int b_local = bl >> 10;
  int mt = (bl >> 5) & 31, nt = bl & 31;
  int b = b0 + b_local;
  int tid = threadIdx.x;
  int tx = tid & 15, ty = tid >> 4;
  int n0 = mt * 64, o0 = nt * 64;

  __shared__ float Ax[64][4], Bx[64][4];
  const float* Xb = X + (size_t)b * N_PTS * 3;
  for (int e = tid; e < 64 * 3; e += 256) {
    int r = e / 3, c = e % 3;
    Ax[r][c] = Xb[(size_t)(n0 + r) * 3 + c];
    Bx[r][c] = Xb[(size_t)(o0 + r) * 3 + c];
  }
  __syncthreads();

  float ar[4][3], br[4][3];
#pragma unroll
  for (int i = 0; i < 4; ++i)
#pragma unroll
    for (int c = 0; c < 3; ++c) {
      ar[i][c] = Ax[ty * 4 + i][c];
      br[i][c] = Bx[tx * 4 + i][c];
    }

  float4 xxr = *(const float4*)&xx[b * N_PTS + n0 + ty * 4];
  float4 xxc = *(const float4*)&xx[b * N_PTS + o0 + tx * 4];
  float xr[4] = {xxr.x, xxr.y, xxr.z, xxr.w};
  float xcv[4] = {xxc.x, xxc.y, xxc.z, xxc.w};

#pragma unroll
  for (int i = 0; i < 4; ++i) {
    float o4[4];
#pragma unroll
    for (int j = 0; j < 4; ++j) {
      float acc = ar[i][0] * br[j][0] + ar[i][1] * br[j][1] + ar[i][2] * br[j][2];
      o4[j] = 2.f * acc - xr[i] - xcv[j];
    }
    *(float4*)&D[((size_t)(b_local * N_PTS) + n0 + ty * 4 + i) * N_PTS + o0 + tx * 4] =
        make_float4(o4[0], o4[1], o4[2], o4[3]);
  }
}

// ---------------------------------------------------------------- distance GEMM (K=64/128)
template<int K>
__global__ void dist_kernel(const float* __restrict__ X, int xstride,
                            const float* __restrict__ xx, int b0,
                            float* __restrict__ D) {
  constexpr int BK = 16, PAD = 68;
  int bl = blockIdx.x;
  int b_local = bl >> 10;
  int mt = (bl >> 5) & 31, nt = bl & 31;
  int b = b0 + b_local;
  int n0 = mt * 64, o0 = nt * 64;
  int tid = threadIdx.x;
  int lr = tid >> 2;            // 0..63
  int lc = (tid & 3) * 4;       // 0,4,8,12
  int tx = tid & 15, ty = tid >> 4;

  __shared__ __align__(16) float As[BK][PAD];
  __shared__ __align__(16) float Bs[BK][PAD];

  const float* Xb = X + (size_t)(b * N_PTS) * xstride;

  float acc[4][4];
#pragma unroll
  for (int i = 0; i < 4; ++i)
#pragma unroll
    for (int j = 0; j < 4; ++j) acc[i][j] = 0.f;

  for (int k0 = 0; k0 < K; k0 += BK) {
    float4 a = *(const float4*)&Xb[(size_t)(n0 + lr) * xstride + k0 + lc];
    float4 bb = *(const float4*)&Xb[(size_t)(o0 + lr) * xstride + k0 + lc];
    __syncthreads();
    As[lc + 0][lr] = a.x; As[lc + 1][lr] = a.y;
    As[lc + 2][lr] = a.z; As[lc + 3][lr] = a.w;
    Bs[lc + 0][lr] = bb.x; Bs[lc + 1][lr] = bb.y;
    Bs[lc + 2][lr] = bb.z; Bs[lc + 3][lr] = bb.w;
    __syncthreads();
#pragma unroll
    for (int kk = 0; kk < BK; ++kk) {
      float4 av = *(const float4*)&As[kk][ty * 4];
      float4 bv = *(const float4*)&Bs[kk][tx * 4];
      float ar[4] = {av.x, av.y, av.z, av.w};
      float br[4] = {bv.x, bv.y, bv.z, bv.w};
#pragma unroll
      for (int i = 0; i < 4; ++i)
#pragma unroll
        for (int j = 0; j < 4; ++j) acc[i][j] += ar[i] * br[j];
    }
  }

  float4 xxr = *(const float4*)&xx[b * N_PTS + n0 + ty * 4];
  float4 xxc = *(const float4*)&xx[b * N_PTS + o0 + tx * 4];
  float xr[4] = {xxr.x, xxr.y, xxr.z, xxr.w};
  float xcv[4] = {xxc.x, xxc.y, xxc.z, xxc.w};
#pragma unroll
  for (int i = 0; i < 4; ++i) {
    float4 o4 = {2.f * acc[i][0] - xr[i] - xcv[0],
                 2.f * acc[i][1] - xr[i] - xcv[1],
                 2.f * acc[i][2] - xr[i] - xcv[2],
                 2.f * acc[i][3] - xr[i] - xcv[3]};
    *(float4*)&D[((size_t)(b_local * N_PTS) + n0 + ty * 4 + i) * N_PTS + o0 + tx * 4] = o4;
  }
}

// ---------------------------------------------------------------- top-20 (wave per row)
__global__ void topk_kernel(const float* __restrict__ D, int b0,
                            int* __restrict__ knn_out) {
  int row = blockIdx.x * 4 + (threadIdx.x >> 6);  // local row in this pass
  int lane = threadIdx.x & 63;
  const float* dr = D + (size_t)row * N_PTS;

  float v[32];
#pragma unroll
  for (int i = 0; i < 32; ++i) v[i] = dr[i * 64 + lane];

  int out_base = (b0 * N_PTS + row) * KNN_K;
  for (int sel = 0; sel < KNN_K; ++sel) {
    float bv = -FLT_MAX; int bi = 0x3fffffff;
#pragma unroll
    for (int i = 0; i < 32; ++i) {
      if (v[i] > bv) { bv = v[i]; bi = i * 64 + lane; }
    }
#pragma unroll
    for (int off = 32; off > 0; off >>= 1) {
      float ov = __shfl_xor(bv, off);
      int   oi = __shfl_xor(bi, off);
      if (ov > bv || (ov == bv && oi < bi)) { bv = ov; bi = oi; }
    }
    if (lane == 0) knn_out[out_base + sel] = bi;
    if ((bi & 63) == lane) {
#pragma unroll
      for (int i = 0; i < 32; ++i)
        if (bi == i * 64 + lane) v[i] = -FLT_MAX;
    }
  }
}

// ---------------------------------------------------------------- W' prep
__global__ void prep_wp_kernel(const float* __restrict__ W,
                               float* __restrict__ Wp, int O, int C) {
  int t = blockIdx.x * 256 + threadIdx.x;
  if (t >= 2 * O * C) return;
  int o = t / C, c = t % C;
  Wp[t] = (o < O) ? W[(size_t)o * 2 * C + c]
                  : (W[(size_t)(o - O) * 2 * C + C + c] -
                     W[(size_t)(o - O) * 2 * C + c]);
}

// ---------------------------------------------------------------- layer-1 uv (K=3)
__global__ void gemm_uv3_kernel(const float* __restrict__ x,
                                const float* __restrict__ Wp,
                                float* __restrict__ out) {
  int t = blockIdx.x * 256 + threadIdx.x;
  if (t >= BATCH * N_PTS * 128) return;
  int n = t >> 7, o = t & 127;
  const float* xr = x + (size_t)n * 3;
  const float* wr = Wp + (size_t)o * 3;
  out[t] = xr[0] * wr[0] + xr[1] * wr[1] + xr[2] * wr[2];
}

// ---------------------------------------------------------------- tiled uv GEMM
template<int NCOLS, int K>
__global__ void gemm_uv_kernel(const float* __restrict__ X, int xstride,
                               const float* __restrict__ Wp,
                               float* __restrict__ out) {
  constexpr int BM = 64, BN = 64, BK = 16, PAD = 68;
  constexpr int NT = NCOLS / BN;
  int mt = blockIdx.x / NT;
  int nt = blockIdx.x % NT;
  int n0 = mt * BM, o0 = nt * BN;
  int tid = threadIdx.x;
  int lr = tid >> 2;
  int lc = (tid & 3) * 4;
  int tx = tid & 15, ty = tid >> 4;

  __shared__ __align__(16) float As[BK][PAD];
  __shared__ __align__(16) float Bs[BK][PAD];

  float acc[4][4];
#pragma unroll
  for (int i = 0; i < 4; ++i)
#pragma unroll
    for (int j = 0; j < 4; ++j) acc[i][j] = 0.f;

  for (int k0 = 0; k0 < K; k0 += BK) {
    float4 a = *(const float4*)&X[(size_t)(n0 + lr) * xstride + k0 + lc];
    float4 bb = *(const float4*)&Wp[(size_t)(o0 + lr) * K + k0 + lc];
    __syncthreads();
    As[lc + 0][lr] = a.x; As[lc + 1][lr] = a.y;
    As[lc + 2][lr] = a.z; As[lc + 3][lr] = a.w;
    Bs[lc + 0][lr] = bb.x; Bs[lc + 1][lr] = bb.y;
    Bs[lc + 2][lr] = bb.z; Bs[lc + 3][lr] = bb.w;
    __syncthreads();
#pragma unroll
    for (int kk = 0; kk < BK; ++kk) {
      float4 av = *(const float4*)&As[kk][ty * 4];
      float4 bv = *(const float4*)&Bs[kk][tx * 4];
      float ar[4] = {av.x, av.y, av.z, av.w};
      float br[4] = {bv.x, bv.y, bv.z, bv.w};
#pragma unroll
      for (int i = 0; i < 4; ++i)
#pragma unroll
        for (int j = 0; j < 4; ++j) acc[i][j] += ar[i] * br[j];
    }
  }
#pragma unroll
  for (int i = 0; i < 4; ++i) {
    float4 o4 = {acc[i][0], acc[i][1], acc[i][2], acc[i][3]};
    *(float4*)&out[(size_t)(n0 + ty * 4 + i) * NCOLS + o0 + tx * 4] = o4;
  }
}

// ---------------------------------------------------------------- edge gather+max
template<int O>
__global__ void edge_max_kernel(const float* __restrict__ uv,
                                const int* __restrict__ knn_idx,
                                const float* __restrict__ gamma,
                                const float* __restrict__ beta,
                                float* __restrict__ out, int out_stride) {
  constexpr int P = 256 / O;
  int tid = threadIdx.x;
  int p = tid / O, o = tid % O;
  int n = blockIdx.x * P + p;
  int b = n / N_PTS;
  float v = uv[(size_t)n * (2 * O) + O + o];
  float g = gamma[o], be = beta[o];
  const int* ir = knn_idx + (size_t)n * KNN_K;
  int mk[KNN_K];
#pragma unroll
  for (int k = 0; k < KNN_K; ++k) mk[k] = ir[k];
  float mx = -FLT_MAX;
#pragma unroll
  for (int k = 0; k < KNN_K; ++k) {
    float u = uv[(size_t)(b * N_PTS + mk[k]) * (2 * O) + o];
    float y = g * ((u + v) * BN_SCALE_F) + be;
    y = (y > 0.f) ? y : 0.2f * y;
    mx = fmaxf(mx, y);
  }
  out[(size_t)n * out_stride + o] = mx;
}

// ---------------------------------------------------------------- W5 GEMM + pooling partials
__global__ void gemm_w5_kernel(const float* __restrict__ xc,
                               const float* __restrict__ W5,
                               const float* __restrict__ g5,
                               const float* __restrict__ b5,
                               float* __restrict__ pmax,
                               float* __restrict__ psum) {
  constexpr int BM = 64, BN = 64, BK = 16, PAD = 68;
  constexpr int NT = 1024 / BN;  // 16
  int mt = blockIdx.x / NT;
  int nt = blockIdx.x % NT;
  int n0 = mt * BM, o0 = nt * BN;
  int tid = threadIdx.x;
  int lr = tid >> 2;
  int lc = (tid & 3) * 4;
  int tx = tid & 15, ty = tid >> 4;

  __shared__ __align__(16) float As[BK][PAD];
  __shared__ __align__(16) float Bs[BK][PAD];

  float acc[4][4];
#pragma unroll
  for (int i = 0; i < 4; ++i)
#pragma unroll
    for (int j = 0; j < 4; ++j) acc[i][j] = 0.f;

  for (int k0 = 0; k0 < XC_CH; k0 += BK) {
    float4 a = *(const float4*)&xc[(size_t)(n0 + lr) * XC_CH + k0 + lc];
    float4 bb = *(const float4*)&W5[(size_t)(o0 + lr) * XC_CH + k0 + lc];
    __syncthreads();
    As[lc + 0][lr] = a.x; As[lc + 1][lr] = a.y;
    As[lc + 2][lr] = a.z; As[lc + 3][lr] = a.w;
    Bs[lc + 0][lr] = bb.x; Bs[lc + 1][lr] = bb.y;
    Bs[lc + 2][lr] = bb.z; Bs[lc + 3][lr] = bb.w;
    __syncthreads();
#pragma unroll
    for (int kk = 0; kk < BK; ++kk) {
      float4 av = *(const float4*)&As[kk][ty * 4];
      float4 bv = *(const float4*)&Bs[kk][tx * 4];
      float ar[4] = {av.x, av.y, av.z, av.w};
      float br[4] = {bv.x, bv.y, bv.z, bv.w};
#pragma unroll
      for (int i = 0; i < 4; ++i)
#pragma unroll
        for (int j = 0; j < 4; ++j) acc[i][j] += ar[i] * br[j];
    }
  }
  __syncthreads();
  float4 gv = *(const float4*)&g5[o0 + tx * 4];
  float4 bvv = *(const float4*)&b5[o0 + tx * 4];
  float gr[4] = {gv.x, gv.y, gv.z, gv.w};
  float br2[4] = {bvv.x, bvv.y, bvv.z, bvv.w};
#pragma unroll
  for (int j = 0; j < 4; ++j) {
    float m = -FLT_MAX, s = 0.f;
#pragma unroll
    for (int i = 0; i < 4; ++i) {
      float y = gr[j] * (acc[i][j] * BN_SCALE_F) + br2[j];
      y = (y > 0.f) ? y : 0.2f * y;
      m = fmaxf(m, y);
      s += y;
    }
    As[ty][tx * 4 + j] = m;
    Bs[ty][tx * 4 + j] = s;
  }
  __syncthreads();
  if (tid < 64) {
    float m = As[0][tid], s = Bs[0][tid];
#pragma unroll
    for (int i = 1; i < 16; ++i) { m = fmaxf(m, As[i][tid]); s += Bs[i][tid]; }
    int b = n0 / N_PTS, ch = (n0 % N_PTS) / BM;
    size_t off = (size_t)(b * 32 + ch) * 1024 + o0 + tid;
    pmax[off] = m;
    psum[off] = s;
  }
}

// ---------------------------------------------------------------- FC head
__global__ void head_kernel(const float* __restrict__ pmax,
                            const float* __restrict__ psum,
                            const float* __restrict__ L1,
                            const float* __restrict__ g6, const float* __restrict__ b6,
                            const float* __restrict__ L2, const float* __restrict__ L2b,
                            const float* __restrict__ g7, const float* __restrict__ b7,
                            const float* __restrict__ L3, const float* __restrict__ L3b,
                            float* __restrict__ out) {
  constexpr int NCH = 32;
  int b = blockIdx.x;
  int tid = threadIdx.x;
  __shared__ float gvec[2048];
  __shared__ float h1[512];
  __shared__ float h2[256];

  for (int o = tid; o < 1024; o += 256) {
    float mx = -FLT_MAX, sm = 0.f;
    for (int ch = 0; ch < NCH; ++ch) {
      size_t idx = (size_t)(b * NCH + ch) * 1024 + o;
      mx = fmaxf(mx, pmax[idx]);
      sm += psum[idx];
    }
    gvec[o] = mx;
    gvec[1024 + o] = sm * (1.f / 2048.f);
  }
  __syncthreads();
  for (int o = tid; o < 512; o += 256) {
    const float* w = &L1[(size_t)o * 2048];
    float s = 0.f;
    for (int c = 0; c < 2048; ++c) s += w[c] * gvec[c];
    float y = g6[o] * (s * BN_SCALE_F) + b6[o];
    h1[o] = (y > 0.f) ? y : 0.2f * y;
  }
  __syncthreads();
  if (tid < 256) {
    const float* w = &L2[(size_t)tid * 512];
    float s = L2b[tid];
    for (int c = 0; c < 512; ++c) s += w[c] * h1[c];
    float y = g7[tid] * (s * BN_SCALE_F) + b7[tid];
    h2[tid] = (y > 0.f) ? y : 0.2f * y;
  }
  __syncthreads();
  if (tid < 10) {
    const float* w = &L3[(size_t)tid * 256];
    float s = L3b[tid];
    for (int c = 0; c < 256; ++c) s += w[c] * h2[c];
    out[b * 10 + tid] = s;
  }
}

// ---------------------------------------------------------------- launch
extern "C" void kernel_launch(void* const* d_in, const int* in_sizes, int n_in,
                              void* d_out, int out_size, void* d_ws, size_t ws_size,
                              hipStream_t stream) {
  const float* x   = (const float*)d_in[0];
  const float* W1  = (const float*)d_in[1];
  const float* g1  = (const float*)d_in[2];
  const float* b1  = (const float*)d_in[3];
  const float* W2  = (const float*)d_in[4];
  const float* g2  = (const float*)d_in[5];
  const float* b2  = (const float*)d_in[6];
  const float* W3  = (const float*)d_in[7];
  const float* g3  = (const float*)d_in[8];
  const float* b3  = (const float*)d_in[9];
  const float* W4  = (const float*)d_in[10];
  const float* g4  = (const float*)d_in[11];
  const float* b4  = (const float*)d_in[12];
  const float* W5  = (const float*)d_in[13];
  const float* g5  = (const float*)d_in[14];
  const float* b5  = (const float*)d_in[15];
  const float* L1  = (const float*)d_in[16];
  const float* g6  = (const float*)d_in[17];
  const float* b6  = (const float*)d_in[18];
  const float* L2  = (const float*)d_in[19];
  const float* L2b = (const float*)d_in[20];
  const float* g7  = (const float*)d_in[21];
  const float* b7  = (const float*)d_in[22];
  const float* L3  = (const float*)d_in[23];
  const float* L3b = (const float*)d_in[24];
  float* out = (float*)d_out;

  // ---- workspace layout: xc | xx | idx | wp | region{ D / uv / pmax+psum }
  const size_t xcF  = (size_t)BATCH * N_PTS * XC_CH;   // 8.39M floats
  const size_t xxF  = BATCH * N_PTS;
  const size_t idxF = (size_t)BATCH * N_PTS * KNN_K;
  const size_t wpF  = 512 * 128;
  const size_t uvF  = (size_t)BATCH * N_PTS * XC_CH;
  const size_t dF1  = (size_t)N_PTS * N_PTS;           // one batch of D

  float* xc  = (float*)d_ws;
  float* xx  = xc + xcF;
  int*   idx = (int*)(xx + xxF);
  float* wp  = (float*)(idx + idxF);
  float* region = wp + wpF;

  size_t baseB = (xcF + xxF + idxF + wpF) * 4;
  int NB = 1;
  for (int cand = 8; cand >= 1; cand >>= 1) {
    size_t regionB = ((size_t)cand * dF1 > uvF ? (size_t)cand * dF1 : uvF) * 4;
    if (baseB + regionB <= ws_size) { NB = cand; break; }
  }

  float* D    = region;
  float* uv   = region;
  float* pmax = region;
  float* psum = region + (size_t)BATCH * 32 * 1024;

  const int NPTS_TOT = BATCH * N_PTS;                  // 16384
  int sq_blocks = (NPTS_TOT + 255) / 256;              // 64

  // ================= layer 1: x (C=3) -> xc[:, 0:64]
  sqnorm_kernel<<<sq_blocks, 256, 0, stream>>>(x, 3, 3, xx);
  for (int b0 = 0; b0 < BATCH; b0 += NB) {
    dist3_kernel<<<NB * 1024, 256, 0, stream>>>(x, xx, b0, D);
    topk_kernel<<<NB * N_PTS / 4, 256, 0, stream>>>(D, b0, idx);
  }
  prep_wp_kernel<<<(2 * 64 * 3 + 255) / 256, 256, 0, stream>>>(W1, wp, 64, 3);
  gemm_uv3_kernel<<<(NPTS_TOT * 128 + 255) / 256, 256, 0, stream>>>(x, wp, uv);
  edge_max_kernel<64><<<NPTS_TOT / 4, 256, 0, stream>>>(uv, idx, g1, b1, xc + 0, XC_CH);

  // ================= layer 2: x1 (C=64) -> xc[:, 64:128]
  sqnorm_kernel<<<sq_blocks, 256, 0, stream>>>(xc + 0, XC_CH, 64, xx);
  for (int b0 = 0; b0 < BATCH; b0 += NB) {
    dist_kernel<64><<<NB * 1024, 256, 0, stream>>>(xc + 0, XC_CH, xx, b0, D);
    topk_kernel<<<NB * N_PTS / 4, 256, 0, stream>>>(D, b0, idx);
  }
  prep_wp_kernel<<<(2 * 64 * 64 + 255) / 256, 256, 0, stream>>>(W2, wp, 64, 64);
  gemm_uv_kernel<128, 64><<<(NPTS_TOT / 64) * (128 / 64), 256, 0, stream>>>(
      xc + 0, XC_CH, wp, uv);
  edge_max_kernel<64><<<NPTS_TOT / 4, 256, 0, stream>>>(uv, idx, g2, b2, xc + 64, XC_CH);

  // ================= layer 3: x2 (C=64) -> xc[:, 128:256]
  sqnorm_kernel<<<sq_blocks, 256, 0, stream>>>(xc + 64, XC_CH, 64, xx);
  for (int b0 = 0; b0 < BATCH; b0 += NB) {
    dist_kernel<64><<<NB * 1024, 256, 0, stream>>>(xc + 64, XC_CH, xx, b0, D);
    topk_kernel<<<NB * N_PTS / 4, 256, 0, stream>>>(D, b0, idx);
  }
  prep_wp_kernel<<<(2 * 128 * 64 + 255) / 256, 256, 0, stream>>>(W3, wp, 128, 64);
  gemm_uv_kernel<256, 64><<<(NPTS_TOT / 64) * (256 / 64), 256, 0, stream>>>(
      xc + 64, XC_CH, wp, uv);
  edge_max_kernel<128><<<NPTS_TOT / 2, 256, 0, stream>>>(uv, idx, g3, b3, xc + 128, XC_CH);

  // ================= layer 4: x3 (C=128) -> xc[:, 256:512]
  sqnorm_kernel<<<sq_blocks, 256, 0, stream>>>(xc + 128, XC_CH, 128, xx);
  for (int b0 = 0; b0 < BATCH; b0 += NB) {
    dist_kernel<128><<<NB * 1024, 256, 0, stream>>>(xc + 128, XC_CH, xx, b0, D);
    topk_kernel<<<NB * N_PTS / 4, 256, 0, stream>>>(D, b0, idx);
  }
  prep_wp_kernel<<<(2 * 256 * 128 + 255) / 256, 256, 0, stream>>>(W4, wp, 256, 128);
  gemm_uv_kernel<512, 128><<<(NPTS_TOT / 64) * (512 / 64), 256, 0, stream>>>(
      xc + 128, XC_CH, wp, uv);
  edge_max_kernel<256><<<NPTS_TOT, 256, 0, stream>>>(uv, idx, g4, b4, xc + 256, XC_CH);

  // ================= W5 GEMM + pooling, FC head
  gemm_w5_kernel<<<(NPTS_TOT / 64) * 16, 256, 0, stream>>>(xc, W5, g5, b5, pmax, psum);
  head_kernel<<<BATCH, 256, 0, stream>>>(pmax, psum, L1, g6, b6,
                                         L2, L2b, g7, b7, L3, L3b, out);
}

// Round 5
// 1054.241 us; speedup vs baseline: 7.8894x; 1.3114x over previous
//
#include <hip/hip_runtime.h>
#include <cfloat>

#define N_PTS 2048
#define BATCH 8
#define KNN_K 20
#define XC_CH 512

constexpr float BN_SCALE_F = 0.9999950000374997f; // 1/sqrt(1+1e-5)

typedef _Float16 h8 __attribute__((ext_vector_type(8)));
typedef _Float16 h4v __attribute__((ext_vector_type(4)));
typedef float f32x4 __attribute__((ext_vector_type(4)));

// ---------------------------------------------------------------- sqnorm
__global__ void sqnorm_kernel(const float* __restrict__ in, int stride, int C,
                              float* __restrict__ xx) {
  int i = blockIdx.x * blockDim.x + threadIdx.x;
  if (i >= BATCH * N_PTS) return;
  const float* row = in + (size_t)i * stride;
  float s = 0.f;
  for (int c = 0; c < C; ++c) { float v = row[c]; s += v * v; }
  xx[i] = s;
}

// ---------------------------------------------------------------- fp32->f16 hi/lo split (packed out)
template<int C>
__global__ void split_f16_kernel(const float* __restrict__ in, int stride,
                                 _Float16* __restrict__ h,
                                 _Float16* __restrict__ l) {
  int t = blockIdx.x * 256 + threadIdx.x;    // float4 index, grid exact
  int r = t / (C / 4);
  int c4 = (t % (C / 4)) * 4;
  float4 v = *(const float4*)&in[(size_t)r * stride + c4];
  h4v hv, lv;
  hv.x = (_Float16)v.x; lv.x = (_Float16)(v.x - (float)hv.x);
  hv.y = (_Float16)v.y; lv.y = (_Float16)(v.y - (float)hv.y);
  hv.z = (_Float16)v.z; lv.z = (_Float16)(v.z - (float)hv.z);
  hv.w = (_Float16)v.w; lv.w = (_Float16)(v.w - (float)hv.w);
  *(h4v*)&h[(size_t)r * C + c4] = hv;
  *(h4v*)&l[(size_t)r * C + c4] = lv;
}

// ---------------------------------------------------------------- fp32->f16 convert (packed)
__global__ void cvt_f16_kernel(const float* __restrict__ in,
                               _Float16* __restrict__ out, int n4) {
  int t = blockIdx.x * 256 + threadIdx.x;
  if (t >= n4) return;
  float4 v = ((const float4*)in)[t];
  h4v o;
  o.x = (_Float16)v.x; o.y = (_Float16)v.y;
  o.z = (_Float16)v.z; o.w = (_Float16)v.w;
  ((h4v*)out)[t] = o;
}

// ---------------------------------------------------------------- distance GEMM (C=3, fp32)
__global__ void dist3_kernel(const float* __restrict__ X,
                             const float* __restrict__ xx, int b0,
                             float* __restrict__ D) {
  int bl = blockIdx.x;
  int b_local = bl >> 10;
  int mt = (bl >> 5) & 31, nt = bl & 31;
  int b = b0 + b_local;
  int tid = threadIdx.x;
  int tx = tid & 15, ty = tid >> 4;
  int n0 = mt * 64, o0 = nt * 64;

  __shared__ float Ax[64][4], Bx[64][4];
  const float* Xb = X + (size_t)b * N_PTS * 3;
  for (int e = tid; e < 64 * 3; e += 256) {
    int r = e / 3, c = e % 3;
    Ax[r][c] = Xb[(size_t)(n0 + r) * 3 + c];
    Bx[r][c] = Xb[(size_t)(o0 + r) * 3 + c];
  }
  __syncthreads();

  float ar[4][3], br[4][3];
#pragma unroll
  for (int i = 0; i < 4; ++i)
#pragma unroll
    for (int c = 0; c < 3; ++c) {
      ar[i][c] = Ax[ty * 4 + i][c];
      br[i][c] = Bx[tx * 4 + i][c];
    }

  float4 xxr = *(const float4*)&xx[b * N_PTS + n0 + ty * 4];
  float4 xxc = *(const float4*)&xx[b * N_PTS + o0 + tx * 4];
  float xr[4] = {xxr.x, xxr.y, xxr.z, xxr.w};
  float xcv[4] = {xxc.x, xxc.y, xxc.z, xxc.w};

#pragma unroll
  for (int i = 0; i < 4; ++i) {
    float o4[4];
#pragma unroll
    for (int j = 0; j < 4; ++j) {
      float acc = ar[i][0] * br[j][0] + ar[i][1] * br[j][1] + ar[i][2] * br[j][2];
      o4[j] = 2.f * acc - xr[i] - xcv[j];
    }
    *(float4*)&D[((size_t)(b_local * N_PTS) + n0 + ty * 4 + i) * N_PTS + o0 + tx * 4] =
        make_float4(o4[0], o4[1], o4[2], o4[3]);
  }
}

// ---------------------------------------------------------------- MFMA distance GEMM (split f16)
// D = 2*(X X^T) - xx_i - xx_j via hi/lo split: X.Y ~= hh + hl + lh.
template<int K>
__global__ __launch_bounds__(256, 2)
void dist_mfma_kernel(const _Float16* __restrict__ Xh,
                      const _Float16* __restrict__ Xl,
                      const float* __restrict__ xx, int b0,
                      float* __restrict__ D) {
  constexpr int ST = 72;   // LDS row stride in f16 (64 + 8 pad)
  __shared__ __align__(16) _Float16 sm[4 * 128 * ST];
  _Float16* Ah = sm;
  _Float16* Al = sm + 128 * ST;
  _Float16* Bh = sm + 2 * 128 * ST;
  _Float16* Bl = sm + 3 * 128 * ST;

  int blk = blockIdx.x;
  int b_local = blk >> 8;
  int mblk = (blk >> 4) & 15, nblk = blk & 15;
  int b = b0 + b_local;
  int row0 = mblk * 128, col0 = nblk * 128;
  int tid = threadIdx.x;
  int wave = tid >> 6, lane = tid & 63;
  int wr = wave >> 1, wc = wave & 1;
  int quad = lane >> 4, l16 = lane & 15;

  const _Float16* XhB = Xh + (size_t)b * N_PTS * K;
  const _Float16* XlB = Xl + (size_t)b * N_PTS * K;

  f32x4 acc[4][4] = {};

  for (int k0 = 0; k0 < K; k0 += 64) {
    __syncthreads();
#pragma unroll
    for (int i = 0; i < 4; ++i) {
      int idx4 = tid + i * 256;
      int r = idx4 >> 3, c8 = idx4 & 7;
      int ko = k0 + c8 * 8;
      *(float4*)&Ah[r * ST + c8 * 8] = *(const float4*)&XhB[(size_t)(row0 + r) * K + ko];
      *(float4*)&Al[r * ST + c8 * 8] = *(const float4*)&XlB[(size_t)(row0 + r) * K + ko];
      *(float4*)&Bh[r * ST + c8 * 8] = *(const float4*)&XhB[(size_t)(col0 + r) * K + ko];
      *(float4*)&Bl[r * ST + c8 * 8] = *(const float4*)&XlB[(size_t)(col0 + r) * K + ko];
    }
    __syncthreads();
#pragma unroll
    for (int ks = 0; ks < 2; ++ks) {
      h8 bh[4], bl[4];
#pragma unroll
      for (int nt = 0; nt < 4; ++nt) {
        int off = (wc * 64 + nt * 16 + l16) * ST + ks * 32 + quad * 8;
        bh[nt] = *(const h8*)&Bh[off];
        bl[nt] = *(const h8*)&Bl[off];
      }
#pragma unroll
      for (int mt = 0; mt < 4; ++mt) {
        int off = (wr * 64 + mt * 16 + l16) * ST + ks * 32 + quad * 8;
        h8 ah = *(const h8*)&Ah[off];
        h8 al = *(const h8*)&Al[off];
#pragma unroll
        for (int nt = 0; nt < 4; ++nt) {
          acc[mt][nt] = __builtin_amdgcn_mfma_f32_16x16x32_f16(ah, bh[nt], acc[mt][nt], 0, 0, 0);
          acc[mt][nt] = __builtin_amdgcn_mfma_f32_16x16x32_f16(ah, bl[nt], acc[mt][nt], 0, 0, 0);
          acc[mt][nt] = __builtin_amdgcn_mfma_f32_16x16x32_f16(al, bh[nt], acc[mt][nt], 0, 0, 0);
        }
      }
    }
  }

  // epilogue: LDS transpose -> coalesced float4 stores with xx correction
  __syncthreads();
  float* S = (float*)sm;               // 128 x 132
#pragma unroll
  for (int mt = 0; mt < 4; ++mt)
#pragma unroll
    for (int nt = 0; nt < 4; ++nt)
#pragma unroll
      for (int i = 0; i < 4; ++i) {
        int rm = wr * 64 + mt * 16 + quad * 4 + i;
        int cn = wc * 64 + nt * 16 + l16;
        S[rm * 132 + cn] = 2.f * acc[mt][nt][i];
      }
  __syncthreads();
  const float* xxb = xx + b * N_PTS;
  float* Db = D + (size_t)b_local * N_PTS * N_PTS;
#pragma unroll
  for (int j = 0; j < 16; ++j) {
    int flat = j * 256 + tid;          // float4 index 0..4095
    int r = flat >> 5, c4 = (flat & 31) * 4;
    float xr = xxb[row0 + r];
    float4 v = *(const float4*)&S[r * 132 + c4];
    float4 xc4 = *(const float4*)&xxb[col0 + c4];
    float4 o = {v.x - xr - xc4.x, v.y - xr - xc4.y,
                v.z - xr - xc4.z, v.w - xr - xc4.w};
    *(float4*)&Db[(size_t)(row0 + r) * N_PTS + col0 + c4] = o;
  }
}

// ---------------------------------------------------------------- MFMA uv GEMM (split f16)
// uv[n][o] = sum_c X[n][c] * Wp[o][c]; M=16384, N=NCOLS, split both operands.
template<int K>
__global__ __launch_bounds__(256, 2)
void uv_mfma_kernel(const _Float16* __restrict__ Xh,
                    const _Float16* __restrict__ Xl,
                    const _Float16* __restrict__ Wph,
                    const _Float16* __restrict__ Wpl,
                    float* __restrict__ out, int NCOLS) {
  constexpr int ST = 72;
  __shared__ __align__(16) _Float16 sm[4 * 128 * ST];
  _Float16* Ah = sm;
  _Float16* Al = sm + 128 * ST;
  _Float16* Bh = sm + 2 * 128 * ST;
  _Float16* Bl = sm + 3 * 128 * ST;

  int nblk = blockIdx.x >> 7, mblk = blockIdx.x & 127;
  int row0 = mblk * 128, col0 = nblk * 128;
  int tid = threadIdx.x;
  int wave = tid >> 6, lane = tid & 63;
  int wr = wave >> 1, wc = wave & 1;
  int quad = lane >> 4, l16 = lane & 15;

  f32x4 acc[4][4] = {};

  for (int k0 = 0; k0 < K; k0 += 64) {
    __syncthreads();
#pragma unroll
    for (int i = 0; i < 4; ++i) {
      int idx4 = tid + i * 256;
      int r = idx4 >> 3, c8 = idx4 & 7;
      int ko = k0 + c8 * 8;
      *(float4*)&Ah[r * ST + c8 * 8] = *(const float4*)&Xh[(size_t)(row0 + r) * K + ko];
      *(float4*)&Al[r * ST + c8 * 8] = *(const float4*)&Xl[(size_t)(row0 + r) * K + ko];
      *(float4*)&Bh[r * ST + c8 * 8] = *(const float4*)&Wph[(size_t)(col0 + r) * K + ko];
      *(float4*)&Bl[r * ST + c8 * 8] = *(const float4*)&Wpl[(size_t)(col0 + r) * K + ko];
    }
    __syncthreads();
#pragma unroll
    for (int ks = 0; ks < 2; ++ks) {
      h8 bh[4], bl[4];
#pragma unroll
      for (int nt = 0; nt < 4; ++nt) {
        int off = (wc * 64 + nt * 16 + l16) * ST + ks * 32 + quad * 8;
        bh[nt] = *(const h8*)&Bh[off];
        bl[nt] = *(const h8*)&Bl[off];
      }
#pragma unroll
      for (int mt = 0; mt < 4; ++mt) {
        int off = (wr * 64 + mt * 16 + l16) * ST + ks * 32 + quad * 8;
        h8 ah = *(const h8*)&Ah[off];
        h8 al = *(const h8*)&Al[off];
#pragma unroll
        for (int nt = 0; nt < 4; ++nt) {
          acc[mt][nt] = __builtin_amdgcn_mfma_f32_16x16x32_f16(ah, bh[nt], acc[mt][nt], 0, 0, 0);
          acc[mt][nt] = __builtin_amdgcn_mfma_f32_16x16x32_f16(ah, bl[nt], acc[mt][nt], 0, 0, 0);
          acc[mt][nt] = __builtin_amdgcn_mfma_f32_16x16x32_f16(al, bh[nt], acc[mt][nt], 0, 0, 0);
        }
      }
    }
  }

  __syncthreads();
  float* S = (float*)sm;
#pragma unroll
  for (int mt = 0; mt < 4; ++mt)
#pragma unroll
    for (int nt = 0; nt < 4; ++nt)
#pragma unroll
      for (int i = 0; i < 4; ++i) {
        int rm = wr * 64 + mt * 16 + quad * 4 + i;
        int cn = wc * 64 + nt * 16 + l16;
        S[rm * 132 + cn] = acc[mt][nt][i];
      }
  __syncthreads();
#pragma unroll
  for (int j = 0; j < 16; ++j) {
    int flat = j * 256 + tid;
    int r = flat >> 5, c4 = (flat & 31) * 4;
    float4 v = *(const float4*)&S[r * 132 + c4];
    *(float4*)&out[(size_t)(row0 + r) * NCOLS + col0 + c4] = v;
  }
}

// ---------------------------------------------------------------- MFMA W5 GEMM + bn/lrelu + pooling
// M=16384, N=1024, K=512, single f16; per-block (128 rows) pooled partials.
__global__ __launch_bounds__(256, 2)
void w5_mfma_kernel(const _Float16* __restrict__ xch,
                    const _Float16* __restrict__ w5h,
                    const float* __restrict__ g5,
                    const float* __restrict__ b5,
                    float* __restrict__ pmax, float* __restrict__ psum) {
  constexpr int ST = 72;
  __shared__ __align__(16) _Float16 sm[2 * 128 * ST];
  __shared__ float redm[2][128], reds[2][128];
  _Float16* Ah = sm;
  _Float16* Bh = sm + 128 * ST;

  int mblk = blockIdx.x >> 3, nblk = blockIdx.x & 7;
  int row0 = mblk * 128, o0 = nblk * 128;
  int tid = threadIdx.x;
  int wave = tid >> 6, lane = tid & 63;
  int wr = wave >> 1, wc = wave & 1;
  int quad = lane >> 4, l16 = lane & 15;

  f32x4 acc[4][4] = {};

  for (int k0 = 0; k0 < XC_CH; k0 += 64) {
    __syncthreads();
    // FIX (round 4 bug): must cover all 1024 (r,c8) pairs -> i < 4.
    // With i < 2 rows 64..127 of Ah/Bh were never staged (undefined LDS ->
    // f16-NaN patterns -> NaN accumulators -> NaN output).
#pragma unroll
    for (int i = 0; i < 4; ++i) {
      int idx4 = tid + i * 256;
      int r = idx4 >> 3, c8 = idx4 & 7;
      int ko = k0 + c8 * 8;
      *(float4*)&Ah[r * ST + c8 * 8] = *(const float4*)&xch[(size_t)(row0 + r) * XC_CH + ko];
      *(float4*)&Bh[r * ST + c8 * 8] = *(const float4*)&w5h[(size_t)(o0 + r) * XC_CH + ko];
    }
    __syncthreads();
#pragma unroll
    for (int ks = 0; ks < 2; ++ks) {
      h8 bh[4];
#pragma unroll
      for (int nt = 0; nt < 4; ++nt)
        bh[nt] = *(const h8*)&Bh[(wc * 64 + nt * 16 + l16) * ST + ks * 32 + quad * 8];
#pragma unroll
      for (int mt = 0; mt < 4; ++mt) {
        h8 ah = *(const h8*)&Ah[(wr * 64 + mt * 16 + l16) * ST + ks * 32 + quad * 8];
#pragma unroll
        for (int nt = 0; nt < 4; ++nt)
          acc[mt][nt] = __builtin_amdgcn_mfma_f32_16x16x32_f16(ah, bh[nt], acc[mt][nt], 0, 0, 0);
      }
    }
  }

  // bn + lrelu + pool over this block's 128 rows
#pragma unroll
  for (int nt = 0; nt < 4; ++nt) {
    int gcol = o0 + wc * 64 + nt * 16 + l16;
    float g = g5[gcol], be = b5[gcol];
    float pm = -FLT_MAX, ps = 0.f;
#pragma unroll
    for (int mt = 0; mt < 4; ++mt)
#pragma unroll
      for (int i = 0; i < 4; ++i) {
        float y = g * (acc[mt][nt][i] * BN_SCALE_F) + be;
        y = (y > 0.f) ? y : 0.2f * y;
        pm = fmaxf(pm, y);
        ps += y;
      }
#pragma unroll
    for (int off = 16; off <= 32; off <<= 1) {
      pm = fmaxf(pm, __shfl_xor(pm, off));
      ps += __shfl_xor(ps, off);
    }
    if (quad == 0) {
      redm[wr][wc * 64 + nt * 16 + l16] = pm;
      reds[wr][wc * 64 + nt * 16 + l16] = ps;
    }
  }
  __syncthreads();
  if (tid < 128) {
    float m = fmaxf(redm[0][tid], redm[1][tid]);
    float s = reds[0][tid] + reds[1][tid];
    int bb = mblk >> 4, ch = mblk & 15;
    size_t off = (size_t)(bb * 16 + ch) * 1024 + o0 + tid;
    pmax[off] = m;
    psum[off] = s;
  }
}

// ---------------------------------------------------------------- top-20 (wave per row)
__global__ void topk_kernel(const float* __restrict__ D, int b0,
                            int* __restrict__ knn_out) {
  int row = blockIdx.x * 4 + (threadIdx.x >> 6);
  int lane = threadIdx.x & 63;
  const float* dr = D + (size_t)row * N_PTS;

  float v[32];
#pragma unroll
  for (int i = 0; i < 32; ++i) v[i] = dr[i * 64 + lane];

  int out_base = (b0 * N_PTS + row) * KNN_K;
  for (int sel = 0; sel < KNN_K; ++sel) {
    float bv = -FLT_MAX; int bi = 0x3fffffff;
#pragma unroll
    for (int i = 0; i < 32; ++i) {
      if (v[i] > bv) { bv = v[i]; bi = i * 64 + lane; }
    }
#pragma unroll
    for (int off = 32; off > 0; off >>= 1) {
      float ov = __shfl_xor(bv, off);
      int   oi = __shfl_xor(bi, off);
      if (ov > bv || (ov == bv && oi < bi)) { bv = ov; bi = oi; }
    }
    if (lane == 0) knn_out[out_base + sel] = bi;
    if ((bi & 63) == lane) {
#pragma unroll
      for (int i = 0; i < 32; ++i)
        if (bi == i * 64 + lane) v[i] = -FLT_MAX;
    }
  }
}

// ---------------------------------------------------------------- W' prep (layer1, fp32)
__global__ void prep_wp3_kernel(const float* __restrict__ W,
                                float* __restrict__ Wp, int O, int C) {
  int t = blockIdx.x * 256 + threadIdx.x;
  if (t >= 2 * O * C) return;
  int o = t / C, c = t % C;
  Wp[t] = (o < O) ? W[(size_t)o * 2 * C + c]
                  : (W[(size_t)(o - O) * 2 * C + C + c] -
                     W[(size_t)(o - O) * 2 * C + c]);
}

// ---------------------------------------------------------------- W' prep (f16 hi/lo)
__global__ void prep_wpf16_kernel(const float* __restrict__ W,
                                  _Float16* __restrict__ Wph,
                                  _Float16* __restrict__ Wpl, int O, int C) {
  int t = blockIdx.x * 256 + threadIdx.x;
  if (t >= 2 * O * C) return;
  int o = t / C, c = t % C;
  float val = (o < O) ? W[(size_t)o * 2 * C + c]
                      : (W[(size_t)(o - O) * 2 * C + C + c] -
                         W[(size_t)(o - O) * 2 * C + c]);
  _Float16 hv = (_Float16)val;
  Wph[t] = hv;
  Wpl[t] = (_Float16)(val - (float)hv);
}

// ---------------------------------------------------------------- layer-1 uv (K=3, fp32)
__global__ void gemm_uv3_kernel(const float* __restrict__ x,
                                const float* __restrict__ Wp,
                                float* __restrict__ out) {
  int t = blockIdx.x * 256 + threadIdx.x;
  if (t >= BATCH * N_PTS * 128) return;
  int n = t >> 7, o = t & 127;
  const float* xr = x + (size_t)n * 3;
  const float* wr = Wp + (size_t)o * 3;
  out[t] = xr[0] * wr[0] + xr[1] * wr[1] + xr[2] * wr[2];
}

// ---------------------------------------------------------------- edge gather+max
template<int O>
__global__ void edge_max_kernel(const float* __restrict__ uv,
                                const int* __restrict__ knn_idx,
                                const float* __restrict__ gamma,
                                const float* __restrict__ beta,
                                float* __restrict__ out, int out_stride) {
  constexpr int P = 256 / O;
  int tid = threadIdx.x;
  int p = tid / O, o = tid % O;
  int n = blockIdx.x * P + p;
  int b = n / N_PTS;
  float v = uv[(size_t)n * (2 * O) + O + o];
  float g = gamma[o], be = beta[o];
  const int* ir = knn_idx + (size_t)n * KNN_K;
  int mk[KNN_K];
#pragma unroll
  for (int k = 0; k < KNN_K; ++k) mk[k] = ir[k];
  float mx = -FLT_MAX;
#pragma unroll
  for (int k = 0; k < KNN_K; ++k) {
    float u = uv[(size_t)(b * N_PTS + mk[k]) * (2 * O) + o];
    float y = g * ((u + v) * BN_SCALE_F) + be;
    y = (y > 0.f) ? y : 0.2f * y;
    mx = fmaxf(mx, y);
  }
  out[(size_t)n * out_stride + o] = mx;
}

// ---------------------------------------------------------------- FC head
__global__ void head_kernel(const float* __restrict__ pmax,
                            const float* __restrict__ psum,
                            const float* __restrict__ L1,
                            const float* __restrict__ g6, const float* __restrict__ b6,
                            const float* __restrict__ L2, const float* __restrict__ L2b,
                            const float* __restrict__ g7, const float* __restrict__ b7,
                            const float* __restrict__ L3, const float* __restrict__ L3b,
                            float* __restrict__ out) {
  constexpr int NCH = 16;
  int b = blockIdx.x;
  int tid = threadIdx.x;
  __shared__ float gvec[2048];
  __shared__ float h1[512];
  __shared__ float h2[256];

  for (int o = tid; o < 1024; o += 256) {
    float mx = -FLT_MAX, sm = 0.f;
    for (int ch = 0; ch < NCH; ++ch) {
      size_t idx = (size_t)(b * NCH + ch) * 1024 + o;
      mx = fmaxf(mx, pmax[idx]);
      sm += psum[idx];
    }
    gvec[o] = mx;
    gvec[1024 + o] = sm * (1.f / 2048.f);
  }
  __syncthreads();
  for (int o = tid; o < 512; o += 256) {
    const float* w = &L1[(size_t)o * 2048];
    float s = 0.f;
    for (int c = 0; c < 2048; ++c) s += w[c] * gvec[c];
    float y = g6[o] * (s * BN_SCALE_F) + b6[o];
    h1[o] = (y > 0.f) ? y : 0.2f * y;
  }
  __syncthreads();
  if (tid < 256) {
    const float* w = &L2[(size_t)tid * 512];
    float s = L2b[tid];
    for (int c = 0; c < 512; ++c) s += w[c] * h1[c];
    float y = g7[tid] * (s * BN_SCALE_F) + b7[tid];
    h2[tid] = (y > 0.f) ? y : 0.2f * y;
  }
  __syncthreads();
  if (tid < 10) {
    const float* w = &L3[(size_t)tid * 256];
    float s = L3b[tid];
    for (int c = 0; c < 256; ++c) s += w[c] * h2[c];
    out[b * 10 + tid] = s;
  }
}

// ---------------------------------------------------------------- launch
extern "C" void kernel_launch(void* const* d_in, const int* in_sizes, int n_in,
                              void* d_out, int out_size, void* d_ws, size_t ws_size,
                              hipStream_t stream) {
  const float* x   = (const float*)d_in[0];
  const float* W1  = (const float*)d_in[1];
  const float* g1  = (const float*)d_in[2];
  const float* b1  = (const float*)d_in[3];
  const float* W2  = (const float*)d_in[4];
  const float* g2  = (const float*)d_in[5];
  const float* b2  = (const float*)d_in[6];
  const float* W3  = (const float*)d_in[7];
  const float* g3  = (const float*)d_in[8];
  const float* b3  = (const float*)d_in[9];
  const float* W4  = (const float*)d_in[10];
  const float* g4  = (const float*)d_in[11];
  const float* b4  = (const float*)d_in[12];
  const float* W5  = (const float*)d_in[13];
  const float* g5  = (const float*)d_in[14];
  const float* b5  = (const float*)d_in[15];
  const float* L1  = (const float*)d_in[16];
  const float* g6  = (const float*)d_in[17];
  const float* b6  = (const float*)d_in[18];
  const float* L2  = (const float*)d_in[19];
  const float* L2b = (const float*)d_in[20];
  const float* g7  = (const float*)d_in[21];
  const float* b7  = (const float*)d_in[22];
  const float* L3  = (const float*)d_in[23];
  const float* L3b = (const float*)d_in[24];
  float* out = (float*)d_out;

  // ---- workspace layout (bytes)
  char* p = (char*)d_ws;
  float* xc = (float*)p;          p += (size_t)16384 * 512 * 4;   // 33.55 MB
  float* xx = (float*)p;          p += 16384 * 4;
  int*   idx = (int*)p;           p += (size_t)16384 * KNN_K * 4; // 1.31 MB
  float* wp = (float*)p;          p += 2 * 64 * 3 * 4 + 64;       // layer1 fp32 W'
  _Float16* wph = (_Float16*)p;   p += (size_t)512 * 128 * 2;
  _Float16* wpl = (_Float16*)p;   p += (size_t)512 * 128 * 2;
  _Float16* Xh = (_Float16*)p;    p += (size_t)16384 * 128 * 2;   // 4.19 MB
  _Float16* Xl = (_Float16*)p;    p += (size_t)16384 * 128 * 2;
  char* region = p;
  size_t baseB = (size_t)(region - (char*)d_ws);

  // region users: D (NB*16.78MB) | uv (33.55MB) | xch+w5h+pools (18.9MB)
  const size_t dB1 = (size_t)N_PTS * N_PTS * 4;
  const size_t uvB = (size_t)16384 * 512 * 4;
  int NB = 1;
  for (int cand = 8; cand >= 1; cand >>= 1) {
    size_t need = (size_t)cand * dB1 > uvB ? (size_t)cand * dB1 : uvB;
    if (baseB + need <= ws_size) { NB = cand; break; }
  }

  float* D  = (float*)region;
  float* uv = (float*)region;
  _Float16* xch = (_Float16*)region;
  _Float16* w5h = xch + (size_t)16384 * 512;
  float* pmax = (float*)(w5h + (size_t)1024 * 512);
  float* psum = pmax + (size_t)BATCH * 16 * 1024;

  const int NPTS_TOT = BATCH * N_PTS;            // 16384
  int sq_blocks = (NPTS_TOT + 255) / 256;        // 64

  // ================= layer 1: x (C=3) -> xc[:, 0:64]
  sqnorm_kernel<<<sq_blocks, 256, 0, stream>>>(x, 3, 3, xx);
  for (int b0 = 0; b0 < BATCH; b0 += NB) {
    dist3_kernel<<<NB * 1024, 256, 0, stream>>>(x, xx, b0, D);
    topk_kernel<<<NB * N_PTS / 4, 256, 0, stream>>>(D, b0, idx);
  }
  prep_wp3_kernel<<<2, 256, 0, stream>>>(W1, wp, 64, 3);
  gemm_uv3_kernel<<<(NPTS_TOT * 128 + 255) / 256, 256, 0, stream>>>(x, wp, uv);
  edge_max_kernel<64><<<NPTS_TOT / 4, 256, 0, stream>>>(uv, idx, g1, b1, xc + 0, XC_CH);

  // ================= layer 2: x1 (C=64) -> xc[:, 64:128]
  sqnorm_kernel<<<sq_blocks, 256, 0, stream>>>(xc + 0, XC_CH, 64, xx);
  split_f16_kernel<64><<<NPTS_TOT * 64 / 4 / 256, 256, 0, stream>>>(xc + 0, XC_CH, Xh, Xl);
  for (int b0 = 0; b0 < BATCH; b0 += NB) {
    dist_mfma_kernel<64><<<NB * 256, 256, 0, stream>>>(Xh, Xl, xx, b0, D);
    topk_kernel<<<NB * N_PTS / 4, 256, 0, stream>>>(D, b0, idx);
  }
  prep_wpf16_kernel<<<(2 * 64 * 64 + 255) / 256, 256, 0, stream>>>(W2, wph, wpl, 64, 64);
  uv_mfma_kernel<64><<<1 * 128, 256, 0, stream>>>(Xh, Xl, wph, wpl, uv, 128);
  edge_max_kernel<64><<<NPTS_TOT / 4, 256, 0, stream>>>(uv, idx, g2, b2, xc + 64, XC_CH);

  // ================= layer 3: x2 (C=64) -> xc[:, 128:256]
  sqnorm_kernel<<<sq_blocks, 256, 0, stream>>>(xc + 64, XC_CH, 64, xx);
  split_f16_kernel<64><<<NPTS_TOT * 64 / 4 / 256, 256, 0, stream>>>(xc + 64, XC_CH, Xh, Xl);
  for (int b0 = 0; b0 < BATCH; b0 += NB) {
    dist_mfma_kernel<64><<<NB * 256, 256, 0, stream>>>(Xh, Xl, xx, b0, D);
    topk_kernel<<<NB * N_PTS / 4, 256, 0, stream>>>(D, b0, idx);
  }
  prep_wpf16_kernel<<<(2 * 128 * 64 + 255) / 256, 256, 0, stream>>>(W3, wph, wpl, 128, 64);
  uv_mfma_kernel<64><<<2 * 128, 256, 0, stream>>>(Xh, Xl, wph, wpl, uv, 256);
  edge_max_kernel<128><<<NPTS_TOT / 2, 256, 0, stream>>>(uv, idx, g3, b3, xc + 128, XC_CH);

  // ================= layer 4: x3 (C=128) -> xc[:, 256:512]
  sqnorm_kernel<<<sq_blocks, 256, 0, stream>>>(xc + 128, XC_CH, 128, xx);
  split_f16_kernel<128><<<NPTS_TOT * 128 / 4 / 256, 256, 0, stream>>>(xc + 128, XC_CH, Xh, Xl);
  for (int b0 = 0; b0 < BATCH; b0 += NB) {
    dist_mfma_kernel<128><<<NB * 256, 256, 0, stream>>>(Xh, Xl, xx, b0, D);
    topk_kernel<<<NB * N_PTS / 4, 256, 0, stream>>>(D, b0, idx);
  }
  prep_wpf16_kernel<<<(2 * 256 * 128 + 255) / 256, 256, 0, stream>>>(W4, wph, wpl, 256, 128);
  uv_mfma_kernel<128><<<4 * 128, 256, 0, stream>>>(Xh, Xl, wph, wpl, uv, 512);
  edge_max_kernel<256><<<NPTS_TOT, 256, 0, stream>>>(uv, idx, g4, b4, xc + 256, XC_CH);

  // ================= W5 (f16 MFMA) + pooling, FC head
  cvt_f16_kernel<<<(16384 * 512 / 4 + 255) / 256, 256, 0, stream>>>(xc, xch, 16384 * 512 / 4);
  cvt_f16_kernel<<<(1024 * 512 / 4 + 255) / 256, 256, 0, stream>>>(W5, w5h, 1024 * 512 / 4);
  w5_mfma_kernel<<<128 * 8, 256, 0, stream>>>(xch, w5h, g5, b5, pmax, psum);
  head_kernel<<<BATCH, 256, 0, stream>>>(pmax, psum, L1, g6, b6,
                                         L2, L2b, g7, b7, L3, L3b, out);
}

// Round 6
// 889.197 us; speedup vs baseline: 9.3538x; 1.1856x over previous
//
#include <hip/hip_runtime.h>
#include <cfloat>

#define N_PTS 2048
#define BATCH 8
#define KNN_K 20
#define XC_CH 512

constexpr float BN_SCALE_F = 0.9999950000374997f; // 1/sqrt(1+1e-5)

typedef _Float16 h8 __attribute__((ext_vector_type(8)));
typedef _Float16 h4v __attribute__((ext_vector_type(4)));
typedef float f32x4 __attribute__((ext_vector_type(4)));

// ---------------------------------------------------------------- sqnorm (layer-1 only, C=3)
__global__ void sqnorm_kernel(const float* __restrict__ in, int stride, int C,
                              float* __restrict__ xx) {
  int i = blockIdx.x * blockDim.x + threadIdx.x;
  if (i >= BATCH * N_PTS) return;
  const float* row = in + (size_t)i * stride;
  float s = 0.f;
  for (int c = 0; c < C; ++c) { float v = row[c]; s += v * v; }
  xx[i] = s;
}

// ---------------------------------------------------------------- fp32->f16 hi/lo split + fused sqnorm
// Coalesced float4 reads; xx[r] = sum(v^2) via subgroup shuffle over the
// C/4 consecutive lanes that share row r.
template<int C>
__global__ void split_sq_kernel(const float* __restrict__ in, int stride,
                                _Float16* __restrict__ h,
                                _Float16* __restrict__ l,
                                float* __restrict__ xx) {
  constexpr int W = C / 4;                   // lanes per row (16 or 32)
  int t = blockIdx.x * 256 + threadIdx.x;    // float4 index, grid exact
  int r = t / W;
  int c4 = (t % W) * 4;
  float4 v = *(const float4*)&in[(size_t)r * stride + c4];
  h4v hv, lv;
  hv.x = (_Float16)v.x; lv.x = (_Float16)(v.x - (float)hv.x);
  hv.y = (_Float16)v.y; lv.y = (_Float16)(v.y - (float)hv.y);
  hv.z = (_Float16)v.z; lv.z = (_Float16)(v.z - (float)hv.z);
  hv.w = (_Float16)v.w; lv.w = (_Float16)(v.w - (float)hv.w);
  *(h4v*)&h[(size_t)r * C + c4] = hv;
  *(h4v*)&l[(size_t)r * C + c4] = lv;
  float p = v.x * v.x + v.y * v.y + v.z * v.z + v.w * v.w;
#pragma unroll
  for (int off = W / 2; off > 0; off >>= 1) p += __shfl_down(p, off, W);
  if ((threadIdx.x & (W - 1)) == 0) xx[r] = p;
}

// ---------------------------------------------------------------- fp32->f16 convert (packed)
__global__ void cvt_f16_kernel(const float* __restrict__ in,
                               _Float16* __restrict__ out, int n4) {
  int t = blockIdx.x * 256 + threadIdx.x;
  if (t >= n4) return;
  float4 v = ((const float4*)in)[t];
  h4v o;
  o.x = (_Float16)v.x; o.y = (_Float16)v.y;
  o.z = (_Float16)v.z; o.w = (_Float16)v.w;
  ((h4v*)out)[t] = o;
}

// ---------------------------------------------------------------- distance GEMM (C=3, fp32)
__global__ void dist3_kernel(const float* __restrict__ X,
                             const float* __restrict__ xx, int b0,
                             float* __restrict__ D) {
  int bl = blockIdx.x;
  int b_local = bl >> 10;
  int mt = (bl >> 5) & 31, nt = bl & 31;
  int b = b0 + b_local;
  int tid = threadIdx.x;
  int tx = tid & 15, ty = tid >> 4;
  int n0 = mt * 64, o0 = nt * 64;

  __shared__ float Ax[64][4], Bx[64][4];
  const float* Xb = X + (size_t)b * N_PTS * 3;
  for (int e = tid; e < 64 * 3; e += 256) {
    int r = e / 3, c = e % 3;
    Ax[r][c] = Xb[(size_t)(n0 + r) * 3 + c];
    Bx[r][c] = Xb[(size_t)(o0 + r) * 3 + c];
  }
  __syncthreads();

  float ar[4][3], br[4][3];
#pragma unroll
  for (int i = 0; i < 4; ++i)
#pragma unroll
    for (int c = 0; c < 3; ++c) {
      ar[i][c] = Ax[ty * 4 + i][c];
      br[i][c] = Bx[tx * 4 + i][c];
    }

  float4 xxr = *(const float4*)&xx[b * N_PTS + n0 + ty * 4];
  float4 xxc = *(const float4*)&xx[b * N_PTS + o0 + tx * 4];
  float xr[4] = {xxr.x, xxr.y, xxr.z, xxr.w};
  float xcv[4] = {xxc.x, xxc.y, xxc.z, xxc.w};

#pragma unroll
  for (int i = 0; i < 4; ++i) {
    float o4[4];
#pragma unroll
    for (int j = 0; j < 4; ++j) {
      float acc = ar[i][0] * br[j][0] + ar[i][1] * br[j][1] + ar[i][2] * br[j][2];
      o4[j] = 2.f * acc - xr[i] - xcv[j];
    }
    *(float4*)&D[((size_t)(b_local * N_PTS) + n0 + ty * 4 + i) * N_PTS + o0 + tx * 4] =
        make_float4(o4[0], o4[1], o4[2], o4[3]);
  }
}

// ---------------------------------------------------------------- MFMA distance GEMM (split f16)
template<int K>
__global__ __launch_bounds__(256, 2)
void dist_mfma_kernel(const _Float16* __restrict__ Xh,
                      const _Float16* __restrict__ Xl,
                      const float* __restrict__ xx, int b0,
                      float* __restrict__ D) {
  constexpr int ST = 72;   // LDS row stride in f16 (64 + 8 pad)
  __shared__ __align__(16) _Float16 sm[4 * 128 * ST];
  _Float16* Ah = sm;
  _Float16* Al = sm + 128 * ST;
  _Float16* Bh = sm + 2 * 128 * ST;
  _Float16* Bl = sm + 3 * 128 * ST;

  int blk = blockIdx.x;
  int b_local = blk >> 8;
  int mblk = (blk >> 4) & 15, nblk = blk & 15;
  int b = b0 + b_local;
  int row0 = mblk * 128, col0 = nblk * 128;
  int tid = threadIdx.x;
  int wave = tid >> 6, lane = tid & 63;
  int wr = wave >> 1, wc = wave & 1;
  int quad = lane >> 4, l16 = lane & 15;

  const _Float16* XhB = Xh + (size_t)b * N_PTS * K;
  const _Float16* XlB = Xl + (size_t)b * N_PTS * K;

  f32x4 acc[4][4] = {};

  for (int k0 = 0; k0 < K; k0 += 64) {
    __syncthreads();
#pragma unroll
    for (int i = 0; i < 4; ++i) {
      int idx4 = tid + i * 256;
      int r = idx4 >> 3, c8 = idx4 & 7;
      int ko = k0 + c8 * 8;
      *(float4*)&Ah[r * ST + c8 * 8] = *(const float4*)&XhB[(size_t)(row0 + r) * K + ko];
      *(float4*)&Al[r * ST + c8 * 8] = *(const float4*)&XlB[(size_t)(row0 + r) * K + ko];
      *(float4*)&Bh[r * ST + c8 * 8] = *(const float4*)&XhB[(size_t)(col0 + r) * K + ko];
      *(float4*)&Bl[r * ST + c8 * 8] = *(const float4*)&XlB[(size_t)(col0 + r) * K + ko];
    }
    __syncthreads();
#pragma unroll
    for (int ks = 0; ks < 2; ++ks) {
      h8 bh[4], bl[4];
#pragma unroll
      for (int nt = 0; nt < 4; ++nt) {
        int off = (wc * 64 + nt * 16 + l16) * ST + ks * 32 + quad * 8;
        bh[nt] = *(const h8*)&Bh[off];
        bl[nt] = *(const h8*)&Bl[off];
      }
#pragma unroll
      for (int mt = 0; mt < 4; ++mt) {
        int off = (wr * 64 + mt * 16 + l16) * ST + ks * 32 + quad * 8;
        h8 ah = *(const h8*)&Ah[off];
        h8 al = *(const h8*)&Al[off];
#pragma unroll
        for (int nt = 0; nt < 4; ++nt) {
          acc[mt][nt] = __builtin_amdgcn_mfma_f32_16x16x32_f16(ah, bh[nt], acc[mt][nt], 0, 0, 0);
          acc[mt][nt] = __builtin_amdgcn_mfma_f32_16x16x32_f16(ah, bl[nt], acc[mt][nt], 0, 0, 0);
          acc[mt][nt] = __builtin_amdgcn_mfma_f32_16x16x32_f16(al, bh[nt], acc[mt][nt], 0, 0, 0);
        }
      }
    }
  }

  // epilogue: LDS transpose -> coalesced float4 stores with xx correction
  __syncthreads();
  float* S = (float*)sm;               // 128 x 132
#pragma unroll
  for (int mt = 0; mt < 4; ++mt)
#pragma unroll
    for (int nt = 0; nt < 4; ++nt)
#pragma unroll
      for (int i = 0; i < 4; ++i) {
        int rm = wr * 64 + mt * 16 + quad * 4 + i;
        int cn = wc * 64 + nt * 16 + l16;
        S[rm * 132 + cn] = 2.f * acc[mt][nt][i];
      }
  __syncthreads();
  const float* xxb = xx + b * N_PTS;
  float* Db = D + (size_t)b_local * N_PTS * N_PTS;
#pragma unroll
  for (int j = 0; j < 16; ++j) {
    int flat = j * 256 + tid;          // float4 index 0..4095
    int r = flat >> 5, c4 = (flat & 31) * 4;
    float xr = xxb[row0 + r];
    float4 v = *(const float4*)&S[r * 132 + c4];
    float4 xc4 = *(const float4*)&xxb[col0 + c4];
    float4 o = {v.x - xr - xc4.x, v.y - xr - xc4.y,
                v.z - xr - xc4.z, v.w - xr - xc4.w};
    *(float4*)&Db[(size_t)(row0 + r) * N_PTS + col0 + c4] = o;
  }
}

// ---------------------------------------------------------------- MFMA uv GEMM (split f16)
template<int K>
__global__ __launch_bounds__(256, 2)
void uv_mfma_kernel(const _Float16* __restrict__ Xh,
                    const _Float16* __restrict__ Xl,
                    const _Float16* __restrict__ Wph,
                    const _Float16* __restrict__ Wpl,
                    float* __restrict__ out, int NCOLS) {
  constexpr int ST = 72;
  __shared__ __align__(16) _Float16 sm[4 * 128 * ST];
  _Float16* Ah = sm;
  _Float16* Al = sm + 128 * ST;
  _Float16* Bh = sm + 2 * 128 * ST;
  _Float16* Bl = sm + 3 * 128 * ST;

  int nblk = blockIdx.x >> 7, mblk = blockIdx.x & 127;
  int row0 = mblk * 128, col0 = nblk * 128;
  int tid = threadIdx.x;
  int wave = tid >> 6, lane = tid & 63;
  int wr = wave >> 1, wc = wave & 1;
  int quad = lane >> 4, l16 = lane & 15;

  f32x4 acc[4][4] = {};

  for (int k0 = 0; k0 < K; k0 += 64) {
    __syncthreads();
#pragma unroll
    for (int i = 0; i < 4; ++i) {
      int idx4 = tid + i * 256;
      int r = idx4 >> 3, c8 = idx4 & 7;
      int ko = k0 + c8 * 8;
      *(float4*)&Ah[r * ST + c8 * 8] = *(const float4*)&Xh[(size_t)(row0 + r) * K + ko];
      *(float4*)&Al[r * ST + c8 * 8] = *(const float4*)&Xl[(size_t)(row0 + r) * K + ko];
      *(float4*)&Bh[r * ST + c8 * 8] = *(const float4*)&Wph[(size_t)(col0 + r) * K + ko];
      *(float4*)&Bl[r * ST + c8 * 8] = *(const float4*)&Wpl[(size_t)(col0 + r) * K + ko];
    }
    __syncthreads();
#pragma unroll
    for (int ks = 0; ks < 2; ++ks) {
      h8 bh[4], bl[4];
#pragma unroll
      for (int nt = 0; nt < 4; ++nt) {
        int off = (wc * 64 + nt * 16 + l16) * ST + ks * 32 + quad * 8;
        bh[nt] = *(const h8*)&Bh[off];
        bl[nt] = *(const h8*)&Bl[off];
      }
#pragma unroll
      for (int mt = 0; mt < 4; ++mt) {
        int off = (wr * 64 + mt * 16 + l16) * ST + ks * 32 + quad * 8;
        h8 ah = *(const h8*)&Ah[off];
        h8 al = *(const h8*)&Al[off];
#pragma unroll
        for (int nt = 0; nt < 4; ++nt) {
          acc[mt][nt] = __builtin_amdgcn_mfma_f32_16x16x32_f16(ah, bh[nt], acc[mt][nt], 0, 0, 0);
          acc[mt][nt] = __builtin_amdgcn_mfma_f32_16x16x32_f16(ah, bl[nt], acc[mt][nt], 0, 0, 0);
          acc[mt][nt] = __builtin_amdgcn_mfma_f32_16x16x32_f16(al, bh[nt], acc[mt][nt], 0, 0, 0);
        }
      }
    }
  }

  __syncthreads();
  float* S = (float*)sm;
#pragma unroll
  for (int mt = 0; mt < 4; ++mt)
#pragma unroll
    for (int nt = 0; nt < 4; ++nt)
#pragma unroll
      for (int i = 0; i < 4; ++i) {
        int rm = wr * 64 + mt * 16 + quad * 4 + i;
        int cn = wc * 64 + nt * 16 + l16;
        S[rm * 132 + cn] = acc[mt][nt][i];
      }
  __syncthreads();
#pragma unroll
  for (int j = 0; j < 16; ++j) {
    int flat = j * 256 + tid;
    int r = flat >> 5, c4 = (flat & 31) * 4;
    float4 v = *(const float4*)&S[r * 132 + c4];
    *(float4*)&out[(size_t)(row0 + r) * NCOLS + col0 + c4] = v;
  }
}

// ---------------------------------------------------------------- MFMA W5 GEMM + bn/lrelu + pooling
__global__ __launch_bounds__(256, 2)
void w5_mfma_kernel(const _Float16* __restrict__ xch,
                    const _Float16* __restrict__ w5h,
                    const float* __restrict__ g5,
                    const float* __restrict__ b5,
                    float* __restrict__ pmax, float* __restrict__ psum) {
  constexpr int ST = 72;
  __shared__ __align__(16) _Float16 sm[2 * 128 * ST];
  __shared__ float redm[2][128], reds[2][128];
  _Float16* Ah = sm;
  _Float16* Bh = sm + 128 * ST;

  int mblk = blockIdx.x >> 3, nblk = blockIdx.x & 7;
  int row0 = mblk * 128, o0 = nblk * 128;
  int tid = threadIdx.x;
  int wave = tid >> 6, lane = tid & 63;
  int wr = wave >> 1, wc = wave & 1;
  int quad = lane >> 4, l16 = lane & 15;

  f32x4 acc[4][4] = {};

  for (int k0 = 0; k0 < XC_CH; k0 += 64) {
    __syncthreads();
#pragma unroll
    for (int i = 0; i < 4; ++i) {       // 1024 (r,c8) pairs: i<4 (round-4 bug was i<2)
      int idx4 = tid + i * 256;
      int r = idx4 >> 3, c8 = idx4 & 7;
      int ko = k0 + c8 * 8;
      *(float4*)&Ah[r * ST + c8 * 8] = *(const float4*)&xch[(size_t)(row0 + r) * XC_CH + ko];
      *(float4*)&Bh[r * ST + c8 * 8] = *(const float4*)&w5h[(size_t)(o0 + r) * XC_CH + ko];
    }
    __syncthreads();
#pragma unroll
    for (int ks = 0; ks < 2; ++ks) {
      h8 bh[4];
#pragma unroll
      for (int nt = 0; nt < 4; ++nt)
        bh[nt] = *(const h8*)&Bh[(wc * 64 + nt * 16 + l16) * ST + ks * 32 + quad * 8];
#pragma unroll
      for (int mt = 0; mt < 4; ++mt) {
        h8 ah = *(const h8*)&Ah[(wr * 64 + mt * 16 + l16) * ST + ks * 32 + quad * 8];
#pragma unroll
        for (int nt = 0; nt < 4; ++nt)
          acc[mt][nt] = __builtin_amdgcn_mfma_f32_16x16x32_f16(ah, bh[nt], acc[mt][nt], 0, 0, 0);
      }
    }
  }

  // bn + lrelu + pool over this block's 128 rows
#pragma unroll
  for (int nt = 0; nt < 4; ++nt) {
    int gcol = o0 + wc * 64 + nt * 16 + l16;
    float g = g5[gcol], be = b5[gcol];
    float pm = -FLT_MAX, ps = 0.f;
#pragma unroll
    for (int mt = 0; mt < 4; ++mt)
#pragma unroll
      for (int i = 0; i < 4; ++i) {
        float y = g * (acc[mt][nt][i] * BN_SCALE_F) + be;
        y = (y > 0.f) ? y : 0.2f * y;
        pm = fmaxf(pm, y);
        ps += y;
      }
#pragma unroll
    for (int off = 16; off <= 32; off <<= 1) {
      pm = fmaxf(pm, __shfl_xor(pm, off));
      ps += __shfl_xor(ps, off);
    }
    if (quad == 0) {
      redm[wr][wc * 64 + nt * 16 + l16] = pm;
      reds[wr][wc * 64 + nt * 16 + l16] = ps;
    }
  }
  __syncthreads();
  if (tid < 128) {
    float m = fmaxf(redm[0][tid], redm[1][tid]);
    float s = reds[0][tid] + reds[1][tid];
    int bb = mblk >> 4, ch = mblk & 15;
    size_t off = (size_t)(bb * 16 + ch) * 1024 + o0 + tid;
    pmax[off] = m;
    psum[off] = s;
  }
}

// ---------------------------------------------------------------- top-20 (wave per row)
__global__ void topk_kernel(const float* __restrict__ D, int b0,
                            int* __restrict__ knn_out) {
  int row = blockIdx.x * 4 + (threadIdx.x >> 6);
  int lane = threadIdx.x & 63;
  const float* dr = D + (size_t)row * N_PTS;

  float v[32];
#pragma unroll
  for (int i = 0; i < 32; ++i) v[i] = dr[i * 64 + lane];

  int out_base = (b0 * N_PTS + row) * KNN_K;
  for (int sel = 0; sel < KNN_K; ++sel) {
    float bv = -FLT_MAX; int bi = 0x3fffffff;
#pragma unroll
    for (int i = 0; i < 32; ++i) {
      if (v[i] > bv) { bv = v[i]; bi = i * 64 + lane; }
    }
#pragma unroll
    for (int off = 32; off > 0; off >>= 1) {
      float ov = __shfl_xor(bv, off);
      int   oi = __shfl_xor(bi, off);
      if (ov > bv || (ov == bv && oi < bi)) { bv = ov; bi = oi; }
    }
    if (lane == 0) knn_out[out_base + sel] = bi;
    if ((bi & 63) == lane) {
#pragma unroll
      for (int i = 0; i < 32; ++i)
        if (bi == i * 64 + lane) v[i] = -FLT_MAX;
    }
  }
}

// ---------------------------------------------------------------- W' prep (layer1, fp32)
__global__ void prep_wp3_kernel(const float* __restrict__ W,
                                float* __restrict__ Wp, int O, int C) {
  int t = blockIdx.x * 256 + threadIdx.x;
  if (t >= 2 * O * C) return;
  int o = t / C, c = t % C;
  Wp[t] = (o < O) ? W[(size_t)o * 2 * C + c]
                  : (W[(size_t)(o - O) * 2 * C + C + c] -
                     W[(size_t)(o - O) * 2 * C + c]);
}

// ---------------------------------------------------------------- W' prep (f16 hi/lo)
__global__ void prep_wpf16_kernel(const float* __restrict__ W,
                                  _Float16* __restrict__ Wph,
                                  _Float16* __restrict__ Wpl, int O, int C) {
  int t = blockIdx.x * 256 + threadIdx.x;
  if (t >= 2 * O * C) return;
  int o = t / C, c = t % C;
  float val = (o < O) ? W[(size_t)o * 2 * C + c]
                      : (W[(size_t)(o - O) * 2 * C + C + c] -
                         W[(size_t)(o - O) * 2 * C + c]);
  _Float16 hv = (_Float16)val;
  Wph[t] = hv;
  Wpl[t] = (_Float16)(val - (float)hv);
}

// ---------------------------------------------------------------- layer-1 uv (K=3, fp32)
__global__ void gemm_uv3_kernel(const float* __restrict__ x,
                                const float* __restrict__ Wp,
                                float* __restrict__ out) {
  int t = blockIdx.x * 256 + threadIdx.x;
  if (t >= BATCH * N_PTS * 128) return;
  int n = t >> 7, o = t & 127;
  const float* xr = x + (size_t)n * 3;
  const float* wr = Wp + (size_t)o * 3;
  out[t] = xr[0] * wr[0] + xr[1] * wr[1] + xr[2] * wr[2];
}

// ---------------------------------------------------------------- edge gather+max
template<int O>
__global__ void edge_max_kernel(const float* __restrict__ uv,
                                const int* __restrict__ knn_idx,
                                const float* __restrict__ gamma,
                                const float* __restrict__ beta,
                                float* __restrict__ out, int out_stride) {
  constexpr int P = 256 / O;
  int tid = threadIdx.x;
  int p = tid / O, o = tid % O;
  int n = blockIdx.x * P + p;
  int b = n / N_PTS;
  float v = uv[(size_t)n * (2 * O) + O + o];
  float g = gamma[o], be = beta[o];
  const int* ir = knn_idx + (size_t)n * KNN_K;
  int mk[KNN_K];
#pragma unroll
  for (int k = 0; k < KNN_K; ++k) mk[k] = ir[k];
  float mx = -FLT_MAX;
#pragma unroll
  for (int k = 0; k < KNN_K; ++k) {
    float u = uv[(size_t)(b * N_PTS + mk[k]) * (2 * O) + o];
    float y = g * ((u + v) * BN_SCALE_F) + be;
    y = (y > 0.f) ? y : 0.2f * y;
    mx = fmaxf(mx, y);
  }
  out[(size_t)n * out_stride + o] = mx;
}

// ---------------------------------------------------------------- head: pool partials -> gvec
__global__ void pool_kernel(const float* __restrict__ pmax,
                            const float* __restrict__ psum,
                            float* __restrict__ gvec) {
  int t = blockIdx.x * 256 + threadIdx.x;   // 8192 threads
  int b = t >> 10, o = t & 1023;
  float mx = -FLT_MAX, sm = 0.f;
#pragma unroll
  for (int ch = 0; ch < 16; ++ch) {
    size_t idx = (size_t)(b * 16 + ch) * 1024 + o;
    mx = fmaxf(mx, pmax[idx]);
    sm += psum[idx];
  }
  gvec[b * 2048 + o] = mx;
  gvec[b * 2048 + 1024 + o] = sm * (1.f / 2048.f);
}

// ---------------------------------------------------------------- head: fc1 (512x2048 GEMV x 8 batches)
// One wave per output row; L1 row held in 8 float4 regs; loop batches.
__global__ void fc1_kernel(const float* __restrict__ gvec,
                           const float* __restrict__ L1,
                           const float* __restrict__ g6, const float* __restrict__ b6,
                           float* __restrict__ h1) {
  int o = blockIdx.x * 4 + (threadIdx.x >> 6);   // 0..511
  int lane = threadIdx.x & 63;
  float4 w[8];
#pragma unroll
  for (int i = 0; i < 8; ++i)
    w[i] = *(const float4*)&L1[(size_t)o * 2048 + i * 256 + lane * 4];
  float g = g6[o], be = b6[o];
  for (int b = 0; b < BATCH; ++b) {
    float s = 0.f;
#pragma unroll
    for (int i = 0; i < 8; ++i) {
      float4 v = *(const float4*)&gvec[b * 2048 + i * 256 + lane * 4];
      s += w[i].x * v.x + w[i].y * v.y + w[i].z * v.z + w[i].w * v.w;
    }
#pragma unroll
    for (int off = 32; off > 0; off >>= 1) s += __shfl_down(s, off);
    if (lane == 0) {
      float y = g * (s * BN_SCALE_F) + be;
      h1[b * 512 + o] = (y > 0.f) ? y : 0.2f * y;
    }
  }
}

// ---------------------------------------------------------------- head: fc2 (256x512 GEMV, wave per (b,o))
__global__ void fc2_kernel(const float* __restrict__ h1,
                           const float* __restrict__ L2, const float* __restrict__ L2b,
                           const float* __restrict__ g7, const float* __restrict__ b7,
                           float* __restrict__ h2) {
  int w = blockIdx.x * 4 + (threadIdx.x >> 6);   // 0..2047
  int lane = threadIdx.x & 63;
  int b = w >> 8, o = w & 255;
  float s = 0.f;
#pragma unroll
  for (int i = 0; i < 2; ++i) {
    float4 wv = *(const float4*)&L2[(size_t)o * 512 + i * 256 + lane * 4];
    float4 hv = *(const float4*)&h1[b * 512 + i * 256 + lane * 4];
    s += wv.x * hv.x + wv.y * hv.y + wv.z * hv.z + wv.w * hv.w;
  }
#pragma unroll
  for (int off = 32; off > 0; off >>= 1) s += __shfl_down(s, off);
  if (lane == 0) {
    float y = g7[o] * ((s + L2b[o]) * BN_SCALE_F) + b7[o];
    h2[b * 256 + o] = (y > 0.f) ? y : 0.2f * y;
  }
}

// ---------------------------------------------------------------- head: fc3 (10x256 GEMV, wave per (b,o))
__global__ void fc3_kernel(const float* __restrict__ h2,
                           const float* __restrict__ L3, const float* __restrict__ L3b,
                           float* __restrict__ out) {
  int w = blockIdx.x * 4 + (threadIdx.x >> 6);   // 0..79
  int lane = threadIdx.x & 63;
  int b = w / 10, o = w - b * 10;
  float4 wv = *(const float4*)&L3[(size_t)o * 256 + lane * 4];
  float4 hv = *(const float4*)&h2[b * 256 + lane * 4];
  float s = wv.x * hv.x + wv.y * hv.y + wv.z * hv.z + wv.w * hv.w;
#pragma unroll
  for (int off = 32; off > 0; off >>= 1) s += __shfl_down(s, off);
  if (lane == 0) out[b * 10 + o] = s + L3b[o];
}

// ---------------------------------------------------------------- launch
extern "C" void kernel_launch(void* const* d_in, const int* in_sizes, int n_in,
                              void* d_out, int out_size, void* d_ws, size_t ws_size,
                              hipStream_t stream) {
  const float* x   = (const float*)d_in[0];
  const float* W1  = (const float*)d_in[1];
  const float* g1  = (const float*)d_in[2];
  const float* b1  = (const float*)d_in[3];
  const float* W2  = (const float*)d_in[4];
  const float* g2  = (const float*)d_in[5];
  const float* b2  = (const float*)d_in[6];
  const float* W3  = (const float*)d_in[7];
  const float* g3  = (const float*)d_in[8];
  const float* b3  = (const float*)d_in[9];
  const float* W4  = (const float*)d_in[10];
  const float* g4  = (const float*)d_in[11];
  const float* b4  = (const float*)d_in[12];
  const float* W5  = (const float*)d_in[13];
  const float* g5  = (const float*)d_in[14];
  const float* b5  = (const float*)d_in[15];
  const float* L1  = (const float*)d_in[16];
  const float* g6  = (const float*)d_in[17];
  const float* b6  = (const float*)d_in[18];
  const float* L2  = (const float*)d_in[19];
  const float* L2b = (const float*)d_in[20];
  const float* g7  = (const float*)d_in[21];
  const float* b7  = (const float*)d_in[22];
  const float* L3  = (const float*)d_in[23];
  const float* L3b = (const float*)d_in[24];
  float* out = (float*)d_out;

  // ---- workspace layout (bytes)
  char* p = (char*)d_ws;
  float* xc = (float*)p;          p += (size_t)16384 * 512 * 4;   // 33.55 MB
  float* xx = (float*)p;          p += 16384 * 4;
  int*   idx = (int*)p;           p += (size_t)16384 * KNN_K * 4; // 1.31 MB
  float* wp = (float*)p;          p += 2 * 64 * 3 * 4 + 64;       // layer1 fp32 W'
  _Float16* wph = (_Float16*)p;   p += (size_t)512 * 128 * 2;
  _Float16* wpl = (_Float16*)p;   p += (size_t)512 * 128 * 2;
  _Float16* Xh = (_Float16*)p;    p += (size_t)16384 * 128 * 2;   // 4.19 MB
  _Float16* Xl = (_Float16*)p;    p += (size_t)16384 * 128 * 2;
  float* gvec = (float*)p;        p += BATCH * 2048 * 4;          // 64 KB
  float* h1g  = (float*)p;        p += BATCH * 512 * 4;
  float* h2g  = (float*)p;        p += BATCH * 256 * 4;
  char* region = p;
  size_t baseB = (size_t)(region - (char*)d_ws);

  // region users: D (NB*16.78MB) | uv (33.55MB) | xch+w5h+pools (18.9MB)
  const size_t dB1 = (size_t)N_PTS * N_PTS * 4;
  const size_t uvB = (size_t)16384 * 512 * 4;
  int NB = 1;
  for (int cand = 8; cand >= 1; cand >>= 1) {
    size_t need = (size_t)cand * dB1 > uvB ? (size_t)cand * dB1 : uvB;
    if (baseB + need <= ws_size) { NB = cand; break; }
  }

  float* D  = (float*)region;
  float* uv = (float*)region;
  _Float16* xch = (_Float16*)region;
  _Float16* w5h = xch + (size_t)16384 * 512;
  float* pmax = (float*)(w5h + (size_t)1024 * 512);
  float* psum = pmax + (size_t)BATCH * 16 * 1024;

  const int NPTS_TOT = BATCH * N_PTS;            // 16384

  // ================= layer 1: x (C=3) -> xc[:, 0:64]
  sqnorm_kernel<<<(NPTS_TOT + 255) / 256, 256, 0, stream>>>(x, 3, 3, xx);
  for (int b0 = 0; b0 < BATCH; b0 += NB) {
    dist3_kernel<<<NB * 1024, 256, 0, stream>>>(x, xx, b0, D);
    topk_kernel<<<NB * N_PTS / 4, 256, 0, stream>>>(D, b0, idx);
  }
  prep_wp3_kernel<<<2, 256, 0, stream>>>(W1, wp, 64, 3);
  gemm_uv3_kernel<<<(NPTS_TOT * 128 + 255) / 256, 256, 0, stream>>>(x, wp, uv);
  edge_max_kernel<64><<<NPTS_TOT / 4, 256, 0, stream>>>(uv, idx, g1, b1, xc + 0, XC_CH);

  // ================= layer 2: x1 (C=64) -> xc[:, 64:128]
  split_sq_kernel<64><<<NPTS_TOT * 16 / 256, 256, 0, stream>>>(xc + 0, XC_CH, Xh, Xl, xx);
  for (int b0 = 0; b0 < BATCH; b0 += NB) {
    dist_mfma_kernel<64><<<NB * 256, 256, 0, stream>>>(Xh, Xl, xx, b0, D);
    topk_kernel<<<NB * N_PTS / 4, 256, 0, stream>>>(D, b0, idx);
  }
  prep_wpf16_kernel<<<(2 * 64 * 64 + 255) / 256, 256, 0, stream>>>(W2, wph, wpl, 64, 64);
  uv_mfma_kernel<64><<<1 * 128, 256, 0, stream>>>(Xh, Xl, wph, wpl, uv, 128);
  edge_max_kernel<64><<<NPTS_TOT / 4, 256, 0, stream>>>(uv, idx, g2, b2, xc + 64, XC_CH);

  // ================= layer 3: x2 (C=64) -> xc[:, 128:256]
  split_sq_kernel<64><<<NPTS_TOT * 16 / 256, 256, 0, stream>>>(xc + 64, XC_CH, Xh, Xl, xx);
  for (int b0 = 0; b0 < BATCH; b0 += NB) {
    dist_mfma_kernel<64><<<NB * 256, 256, 0, stream>>>(Xh, Xl, xx, b0, D);
    topk_kernel<<<NB * N_PTS / 4, 256, 0, stream>>>(D, b0, idx);
  }
  prep_wpf16_kernel<<<(2 * 128 * 64 + 255) / 256, 256, 0, stream>>>(W3, wph, wpl, 128, 64);
  uv_mfma_kernel<64><<<2 * 128, 256, 0, stream>>>(Xh, Xl, wph, wpl, uv, 256);
  edge_max_kernel<128><<<NPTS_TOT / 2, 256, 0, stream>>>(uv, idx, g3, b3, xc + 128, XC_CH);

  // ================= layer 4: x3 (C=128) -> xc[:, 256:512]
  split_sq_kernel<128><<<NPTS_TOT * 32 / 256, 256, 0, stream>>>(xc + 128, XC_CH, Xh, Xl, xx);
  for (int b0 = 0; b0 < BATCH; b0 += NB) {
    dist_mfma_kernel<128><<<NB * 256, 256, 0, stream>>>(Xh, Xl, xx, b0, D);
    topk_kernel<<<NB * N_PTS / 4, 256, 0, stream>>>(D, b0, idx);
  }
  prep_wpf16_kernel<<<(2 * 256 * 128 + 255) / 256, 256, 0, stream>>>(W4, wph, wpl, 256, 128);
  uv_mfma_kernel<128><<<4 * 128, 256, 0, stream>>>(Xh, Xl, wph, wpl, uv, 512);
  edge_max_kernel<256><<<NPTS_TOT, 256, 0, stream>>>(uv, idx, g4, b4, xc + 256, XC_CH);

  // ================= W5 (f16 MFMA) + pooling, GEMV head
  cvt_f16_kernel<<<(16384 * 512 / 4 + 255) / 256, 256, 0, stream>>>(xc, xch, 16384 * 512 / 4);
  cvt_f16_kernel<<<(1024 * 512 / 4 + 255) / 256, 256, 0, stream>>>(W5, w5h, 1024 * 512 / 4);
  w5_mfma_kernel<<<128 * 8, 256, 0, stream>>>(xch, w5h, g5, b5, pmax, psum);
  pool_kernel<<<32, 256, 0, stream>>>(pmax, psum, gvec);
  fc1_kernel<<<128, 256, 0, stream>>>(gvec, L1, g6, b6, h1g);
  fc2_kernel<<<512, 256, 0, stream>>>(h1g, L2, L2b, g7, b7, h2g);
  fc3_kernel<<<20, 256, 0, stream>>>(h2g, L3, L3b, out);
}

// Round 7
// 636.307 us; speedup vs baseline: 13.0713x; 1.3974x over previous
//
#include <hip/hip_runtime.h>
#include <cfloat>

#define N_PTS 2048
#define BATCH 8
#define KNN_K 20
#define XC_CH 512

constexpr float BN_SCALE_F = 0.9999950000374997f; // 1/sqrt(1+1e-5)

typedef _Float16 h8 __attribute__((ext_vector_type(8)));
typedef _Float16 h4v __attribute__((ext_vector_type(4)));
typedef float f32x4 __attribute__((ext_vector_type(4)));

// ---------------------------------------------------------------- sqnorm (layer-1 only, C=3)
__global__ void sqnorm_kernel(const float* __restrict__ in, int stride, int C,
                              float* __restrict__ xx) {
  int i = blockIdx.x * blockDim.x + threadIdx.x;
  if (i >= BATCH * N_PTS) return;
  const float* row = in + (size_t)i * stride;
  float s = 0.f;
  for (int c = 0; c < C; ++c) { float v = row[c]; s += v * v; }
  xx[i] = s;
}

// ---------------------------------------------------------------- fp32->f16 hi/lo split + fused sqnorm
template<int C>
__global__ void split_sq_kernel(const float* __restrict__ in, int stride,
                                _Float16* __restrict__ h,
                                _Float16* __restrict__ l,
                                float* __restrict__ xx) {
  constexpr int W = C / 4;                   // lanes per row (16 or 32)
  int t = blockIdx.x * 256 + threadIdx.x;    // float4 index, grid exact
  int r = t / W;
  int c4 = (t % W) * 4;
  float4 v = *(const float4*)&in[(size_t)r * stride + c4];
  h4v hv, lv;
  hv.x = (_Float16)v.x; lv.x = (_Float16)(v.x - (float)hv.x);
  hv.y = (_Float16)v.y; lv.y = (_Float16)(v.y - (float)hv.y);
  hv.z = (_Float16)v.z; lv.z = (_Float16)(v.z - (float)hv.z);
  hv.w = (_Float16)v.w; lv.w = (_Float16)(v.w - (float)hv.w);
  *(h4v*)&h[(size_t)r * C + c4] = hv;
  *(h4v*)&l[(size_t)r * C + c4] = lv;
  float p = v.x * v.x + v.y * v.y + v.z * v.z + v.w * v.w;
#pragma unroll
  for (int off = W / 2; off > 0; off >>= 1) p += __shfl_down(p, off, W);
  if ((threadIdx.x & (W - 1)) == 0) xx[r] = p;
}

// ---------------------------------------------------------------- fp32->f16 convert (packed)
__global__ void cvt_f16_kernel(const float* __restrict__ in,
                               _Float16* __restrict__ out, int n4) {
  int t = blockIdx.x * 256 + threadIdx.x;
  if (t >= n4) return;
  float4 v = ((const float4*)in)[t];
  h4v o;
  o.x = (_Float16)v.x; o.y = (_Float16)v.y;
  o.z = (_Float16)v.z; o.w = (_Float16)v.w;
  ((h4v*)out)[t] = o;
}

// ---------------------------------------------------------------- distance GEMM (C=3, fp32)
__global__ void dist3_kernel(const float* __restrict__ X,
                             const float* __restrict__ xx, int b0,
                             float* __restrict__ D) {
  int bl = blockIdx.x;
  int b_local = bl >> 10;
  int mt = (bl >> 5) & 31, nt = bl & 31;
  int b = b0 + b_local;
  int tid = threadIdx.x;
  int tx = tid & 15, ty = tid >> 4;
  int n0 = mt * 64, o0 = nt * 64;

  __shared__ float Ax[64][4], Bx[64][4];
  const float* Xb = X + (size_t)b * N_PTS * 3;
  for (int e = tid; e < 64 * 3; e += 256) {
    int r = e / 3, c = e % 3;
    Ax[r][c] = Xb[(size_t)(n0 + r) * 3 + c];
    Bx[r][c] = Xb[(size_t)(o0 + r) * 3 + c];
  }
  __syncthreads();

  float ar[4][3], br[4][3];
#pragma unroll
  for (int i = 0; i < 4; ++i)
#pragma unroll
    for (int c = 0; c < 3; ++c) {
      ar[i][c] = Ax[ty * 4 + i][c];
      br[i][c] = Bx[tx * 4 + i][c];
    }

  float4 xxr = *(const float4*)&xx[b * N_PTS + n0 + ty * 4];
  float4 xxc = *(const float4*)&xx[b * N_PTS + o0 + tx * 4];
  float xr[4] = {xxr.x, xxr.y, xxr.z, xxr.w};
  float xcv[4] = {xxc.x, xxc.y, xxc.z, xxc.w};

#pragma unroll
  for (int i = 0; i < 4; ++i) {
    float o4[4];
#pragma unroll
    for (int j = 0; j < 4; ++j) {
      float acc = ar[i][0] * br[j][0] + ar[i][1] * br[j][1] + ar[i][2] * br[j][2];
      o4[j] = 2.f * acc - xr[i] - xcv[j];
    }
    *(float4*)&D[((size_t)(b_local * N_PTS) + n0 + ty * 4 + i) * N_PTS + o0 + tx * 4] =
        make_float4(o4[0], o4[1], o4[2], o4[3]);
  }
}

// ---------------------------------------------------------------- MFMA distance GEMM (split f16)
template<int K>
__global__ __launch_bounds__(256, 2)
void dist_mfma_kernel(const _Float16* __restrict__ Xh,
                      const _Float16* __restrict__ Xl,
                      const float* __restrict__ xx, int b0,
                      float* __restrict__ D) {
  constexpr int ST = 72;   // LDS row stride in f16 (64 + 8 pad)
  __shared__ __align__(16) _Float16 sm[4 * 128 * ST];
  _Float16* Ah = sm;
  _Float16* Al = sm + 128 * ST;
  _Float16* Bh = sm + 2 * 128 * ST;
  _Float16* Bl = sm + 3 * 128 * ST;

  int blk = blockIdx.x;
  int b_local = blk >> 8;
  int mblk = (blk >> 4) & 15, nblk = blk & 15;
  int b = b0 + b_local;
  int row0 = mblk * 128, col0 = nblk * 128;
  int tid = threadIdx.x;
  int wave = tid >> 6, lane = tid & 63;
  int wr = wave >> 1, wc = wave & 1;
  int quad = lane >> 4, l16 = lane & 15;

  const _Float16* XhB = Xh + (size_t)b * N_PTS * K;
  const _Float16* XlB = Xl + (size_t)b * N_PTS * K;

  f32x4 acc[4][4] = {};

  for (int k0 = 0; k0 < K; k0 += 64) {
    __syncthreads();
#pragma unroll
    for (int i = 0; i < 4; ++i) {
      int idx4 = tid + i * 256;
      int r = idx4 >> 3, c8 = idx4 & 7;
      int ko = k0 + c8 * 8;
      *(float4*)&Ah[r * ST + c8 * 8] = *(const float4*)&XhB[(size_t)(row0 + r) * K + ko];
      *(float4*)&Al[r * ST + c8 * 8] = *(const float4*)&XlB[(size_t)(row0 + r) * K + ko];
      *(float4*)&Bh[r * ST + c8 * 8] = *(const float4*)&XhB[(size_t)(col0 + r) * K + ko];
      *(float4*)&Bl[r * ST + c8 * 8] = *(const float4*)&XlB[(size_t)(col0 + r) * K + ko];
    }
    __syncthreads();
#pragma unroll
    for (int ks = 0; ks < 2; ++ks) {
      h8 bh[4], bl[4];
#pragma unroll
      for (int nt = 0; nt < 4; ++nt) {
        int off = (wc * 64 + nt * 16 + l16) * ST + ks * 32 + quad * 8;
        bh[nt] = *(const h8*)&Bh[off];
        bl[nt] = *(const h8*)&Bl[off];
      }
#pragma unroll
      for (int mt = 0; mt < 4; ++mt) {
        int off = (wr * 64 + mt * 16 + l16) * ST + ks * 32 + quad * 8;
        h8 ah = *(const h8*)&Ah[off];
        h8 al = *(const h8*)&Al[off];
#pragma unroll
        for (int nt = 0; nt < 4; ++nt) {
          acc[mt][nt] = __builtin_amdgcn_mfma_f32_16x16x32_f16(ah, bh[nt], acc[mt][nt], 0, 0, 0);
          acc[mt][nt] = __builtin_amdgcn_mfma_f32_16x16x32_f16(ah, bl[nt], acc[mt][nt], 0, 0, 0);
          acc[mt][nt] = __builtin_amdgcn_mfma_f32_16x16x32_f16(al, bh[nt], acc[mt][nt], 0, 0, 0);
        }
      }
    }
  }

  // epilogue: LDS transpose -> coalesced float4 stores with xx correction
  __syncthreads();
  float* S = (float*)sm;               // 128 x 132
#pragma unroll
  for (int mt = 0; mt < 4; ++mt)
#pragma unroll
    for (int nt = 0; nt < 4; ++nt)
#pragma unroll
      for (int i = 0; i < 4; ++i) {
        int rm = wr * 64 + mt * 16 + quad * 4 + i;
        int cn = wc * 64 + nt * 16 + l16;
        S[rm * 132 + cn] = 2.f * acc[mt][nt][i];
      }
  __syncthreads();
  const float* xxb = xx + b * N_PTS;
  float* Db = D + (size_t)b_local * N_PTS * N_PTS;
#pragma unroll
  for (int j = 0; j < 16; ++j) {
    int flat = j * 256 + tid;          // float4 index 0..4095
    int r = flat >> 5, c4 = (flat & 31) * 4;
    float xr = xxb[row0 + r];
    float4 v = *(const float4*)&S[r * 132 + c4];
    float4 xc4 = *(const float4*)&xxb[col0 + c4];
    float4 o = {v.x - xr - xc4.x, v.y - xr - xc4.y,
                v.z - xr - xc4.z, v.w - xr - xc4.w};
    *(float4*)&Db[(size_t)(row0 + r) * N_PTS + col0 + c4] = o;
  }
}

// ---------------------------------------------------------------- MFMA uv GEMM (split f16)
template<int K>
__global__ __launch_bounds__(256, 2)
void uv_mfma_kernel(const _Float16* __restrict__ Xh,
                    const _Float16* __restrict__ Xl,
                    const _Float16* __restrict__ Wph,
                    const _Float16* __restrict__ Wpl,
                    float* __restrict__ out, int NCOLS) {
  constexpr int ST = 72;
  __shared__ __align__(16) _Float16 sm[4 * 128 * ST];
  _Float16* Ah = sm;
  _Float16* Al = sm + 128 * ST;
  _Float16* Bh = sm + 2 * 128 * ST;
  _Float16* Bl = sm + 3 * 128 * ST;

  int nblk = blockIdx.x >> 7, mblk = blockIdx.x & 127;
  int row0 = mblk * 128, col0 = nblk * 128;
  int tid = threadIdx.x;
  int wave = tid >> 6, lane = tid & 63;
  int wr = wave >> 1, wc = wave & 1;
  int quad = lane >> 4, l16 = lane & 15;

  f32x4 acc[4][4] = {};

  for (int k0 = 0; k0 < K; k0 += 64) {
    __syncthreads();
#pragma unroll
    for (int i = 0; i < 4; ++i) {
      int idx4 = tid + i * 256;
      int r = idx4 >> 3, c8 = idx4 & 7;
      int ko = k0 + c8 * 8;
      *(float4*)&Ah[r * ST + c8 * 8] = *(const float4*)&Xh[(size_t)(row0 + r) * K + ko];
      *(float4*)&Al[r * ST + c8 * 8] = *(const float4*)&Xl[(size_t)(row0 + r) * K + ko];
      *(float4*)&Bh[r * ST + c8 * 8] = *(const float4*)&Wph[(size_t)(col0 + r) * K + ko];
      *(float4*)&Bl[r * ST + c8 * 8] = *(const float4*)&Wpl[(size_t)(col0 + r) * K + ko];
    }
    __syncthreads();
#pragma unroll
    for (int ks = 0; ks < 2; ++ks) {
      h8 bh[4], bl[4];
#pragma unroll
      for (int nt = 0; nt < 4; ++nt) {
        int off = (wc * 64 + nt * 16 + l16) * ST + ks * 32 + quad * 8;
        bh[nt] = *(const h8*)&Bh[off];
        bl[nt] = *(const h8*)&Bl[off];
      }
#pragma unroll
      for (int mt = 0; mt < 4; ++mt) {
        int off = (wr * 64 + mt * 16 + l16) * ST + ks * 32 + quad * 8;
        h8 ah = *(const h8*)&Ah[off];
        h8 al = *(const h8*)&Al[off];
#pragma unroll
        for (int nt = 0; nt < 4; ++nt) {
          acc[mt][nt] = __builtin_amdgcn_mfma_f32_16x16x32_f16(ah, bh[nt], acc[mt][nt], 0, 0, 0);
          acc[mt][nt] = __builtin_amdgcn_mfma_f32_16x16x32_f16(ah, bl[nt], acc[mt][nt], 0, 0, 0);
          acc[mt][nt] = __builtin_amdgcn_mfma_f32_16x16x32_f16(al, bh[nt], acc[mt][nt], 0, 0, 0);
        }
      }
    }
  }

  __syncthreads();
  float* S = (float*)sm;
#pragma unroll
  for (int mt = 0; mt < 4; ++mt)
#pragma unroll
    for (int nt = 0; nt < 4; ++nt)
#pragma unroll
      for (int i = 0; i < 4; ++i) {
        int rm = wr * 64 + mt * 16 + quad * 4 + i;
        int cn = wc * 64 + nt * 16 + l16;
        S[rm * 132 + cn] = acc[mt][nt][i];
      }
  __syncthreads();
#pragma unroll
  for (int j = 0; j < 16; ++j) {
    int flat = j * 256 + tid;
    int r = flat >> 5, c4 = (flat & 31) * 4;
    float4 v = *(const float4*)&S[r * 132 + c4];
    *(float4*)&out[(size_t)(row0 + r) * NCOLS + col0 + c4] = v;
  }
}

// ---------------------------------------------------------------- MFMA W5 GEMM + bn/lrelu + pooling
__global__ __launch_bounds__(256, 2)
void w5_mfma_kernel(const _Float16* __restrict__ xch,
                    const _Float16* __restrict__ w5h,
                    const float* __restrict__ g5,
                    const float* __restrict__ b5,
                    float* __restrict__ pmax, float* __restrict__ psum) {
  constexpr int ST = 72;
  __shared__ __align__(16) _Float16 sm[2 * 128 * ST];
  __shared__ float redm[2][128], reds[2][128];
  _Float16* Ah = sm;
  _Float16* Bh = sm + 128 * ST;

  int mblk = blockIdx.x >> 3, nblk = blockIdx.x & 7;
  int row0 = mblk * 128, o0 = nblk * 128;
  int tid = threadIdx.x;
  int wave = tid >> 6, lane = tid & 63;
  int wr = wave >> 1, wc = wave & 1;
  int quad = lane >> 4, l16 = lane & 15;

  f32x4 acc[4][4] = {};

  for (int k0 = 0; k0 < XC_CH; k0 += 64) {
    __syncthreads();
#pragma unroll
    for (int i = 0; i < 4; ++i) {       // 1024 (r,c8) pairs: i<4
      int idx4 = tid + i * 256;
      int r = idx4 >> 3, c8 = idx4 & 7;
      int ko = k0 + c8 * 8;
      *(float4*)&Ah[r * ST + c8 * 8] = *(const float4*)&xch[(size_t)(row0 + r) * XC_CH + ko];
      *(float4*)&Bh[r * ST + c8 * 8] = *(const float4*)&w5h[(size_t)(o0 + r) * XC_CH + ko];
    }
    __syncthreads();
#pragma unroll
    for (int ks = 0; ks < 2; ++ks) {
      h8 bh[4];
#pragma unroll
      for (int nt = 0; nt < 4; ++nt)
        bh[nt] = *(const h8*)&Bh[(wc * 64 + nt * 16 + l16) * ST + ks * 32 + quad * 8];
#pragma unroll
      for (int mt = 0; mt < 4; ++mt) {
        h8 ah = *(const h8*)&Ah[(wr * 64 + mt * 16 + l16) * ST + ks * 32 + quad * 8];
#pragma unroll
        for (int nt = 0; nt < 4; ++nt)
          acc[mt][nt] = __builtin_amdgcn_mfma_f32_16x16x32_f16(ah, bh[nt], acc[mt][nt], 0, 0, 0);
      }
    }
  }

  // bn + lrelu + pool over this block's 128 rows
#pragma unroll
  for (int nt = 0; nt < 4; ++nt) {
    int gcol = o0 + wc * 64 + nt * 16 + l16;
    float g = g5[gcol], be = b5[gcol];
    float pm = -FLT_MAX, ps = 0.f;
#pragma unroll
    for (int mt = 0; mt < 4; ++mt)
#pragma unroll
      for (int i = 0; i < 4; ++i) {
        float y = g * (acc[mt][nt][i] * BN_SCALE_F) + be;
        y = (y > 0.f) ? y : 0.2f * y;
        pm = fmaxf(pm, y);
        ps += y;
      }
#pragma unroll
    for (int off = 16; off <= 32; off <<= 1) {
      pm = fmaxf(pm, __shfl_xor(pm, off));
      ps += __shfl_xor(ps, off);
    }
    if (quad == 0) {
      redm[wr][wc * 64 + nt * 16 + l16] = pm;
      reds[wr][wc * 64 + nt * 16 + l16] = ps;
    }
  }
  __syncthreads();
  if (tid < 128) {
    float m = fmaxf(redm[0][tid], redm[1][tid]);
    float s = reds[0][tid] + reds[1][tid];
    int bb = mblk >> 4, ch = mblk & 15;
    size_t off = (size_t)(bb * 16 + ch) * 1024 + o0 + tid;
    pmax[off] = m;
    psum[off] = s;
  }
}

// ---------------------------------------------------------------- top-20 (wave per row, cached top-3)
// Each lane caches its local top-3 (value,index). Per round: u64-key butterfly
// argmax (sortable-f32<<32 | ~gidx gives descending value, lower index on tie),
// winner lane pops its cache. Full masked rescan only when a lane's cache is
// exhausted (3rd+ win) -- rare, exec-masked, execz-skipped.
__global__ void topk_kernel(const float* __restrict__ D, int b0,
                            int* __restrict__ knn_out) {
  int row = blockIdx.x * 4 + (threadIdx.x >> 6);
  int lane = threadIdx.x & 63;
  const float* dr = D + (size_t)row * N_PTS;

  float v[32];
#pragma unroll
  for (int i = 0; i < 32; ++i) v[i] = dr[i * 64 + lane];

  // build local top-3 (ascending scan + strict > keeps lowest index on ties)
  float t1 = -FLT_MAX, t2 = -FLT_MAX, t3 = -FLT_MAX;
  int i1 = -1, i2 = -1, i3 = -1;
#pragma unroll
  for (int i = 0; i < 32; ++i) {
    float val = v[i];
    bool g1 = val > t1, g2 = val > t2, g3 = val > t3;
    t3 = g2 ? t2 : (g3 ? val : t3);
    i3 = g2 ? i2 : (g3 ? i : i3);
    t2 = g1 ? t1 : (g2 ? val : t2);
    i2 = g1 ? i1 : (g2 ? i : i2);
    t1 = g1 ? val : t1;
    i1 = g1 ? i : i1;
  }
  unsigned consumed = 0u;
  int out_base = (b0 * N_PTS + row) * KNN_K;

#pragma clang loop unroll(disable)
  for (int sel = 0; sel < KNN_K; ++sel) {
    if (i1 < 0) {                       // refill (rare: lane's 3rd+ win)
      float a1 = -FLT_MAX, a2 = -FLT_MAX, a3 = -FLT_MAX;
      int j1 = -1, j2 = -1, j3 = -1;
#pragma unroll
      for (int i = 0; i < 32; ++i) {
        float val = ((consumed >> i) & 1u) ? -FLT_MAX : v[i];
        bool g1 = val > a1, g2 = val > a2, g3 = val > a3;
        a3 = g2 ? a2 : (g3 ? val : a3);
        j3 = g2 ? j2 : (g3 ? i : j3);
        a2 = g1 ? a1 : (g2 ? val : a2);
        j2 = g1 ? j1 : (g2 ? i : j2);
        a1 = g1 ? val : a1;
        j1 = g1 ? i : j1;
      }
      t1 = a1; i1 = j1; t2 = a2; i2 = j2; t3 = a3; i3 = j3;
    }
    // sortable u64 key: monotone(f32) high, ~gidx low (max => value desc, idx asc)
    unsigned bits = __float_as_uint(t1);
    unsigned enc = bits ^ ((unsigned)((int)bits >> 31) | 0x80000000u);
    unsigned long long key =
        ((unsigned long long)enc << 32) | (unsigned)~(i1 * 64 + lane);
#pragma unroll
    for (int off = 32; off > 0; off >>= 1) {
      unsigned long long ok = __shfl_xor(key, off);
      if (ok > key) key = ok;
    }
    int bi = (int)~(unsigned)key;
    if (lane == 0) knn_out[out_base + sel] = bi;
    if ((bi & 63) == lane) {            // this lane's t1 won: pop cache
      consumed |= 1u << i1;
      t1 = t2; i1 = i2;
      t2 = t3; i2 = i3;
      t3 = -FLT_MAX; i3 = -1;
    }
  }
}

// ---------------------------------------------------------------- W' prep (layer1, fp32)
__global__ void prep_wp3_kernel(const float* __restrict__ W,
                                float* __restrict__ Wp, int O, int C) {
  int t = blockIdx.x * 256 + threadIdx.x;
  if (t >= 2 * O * C) return;
  int o = t / C, c = t % C;
  Wp[t] = (o < O) ? W[(size_t)o * 2 * C + c]
                  : (W[(size_t)(o - O) * 2 * C + C + c] -
                     W[(size_t)(o - O) * 2 * C + c]);
}

// ---------------------------------------------------------------- W' prep (f16 hi/lo)
__global__ void prep_wpf16_kernel(const float* __restrict__ W,
                                  _Float16* __restrict__ Wph,
                                  _Float16* __restrict__ Wpl, int O, int C) {
  int t = blockIdx.x * 256 + threadIdx.x;
  if (t >= 2 * O * C) return;
  int o = t / C, c = t % C;
  float val = (o < O) ? W[(size_t)o * 2 * C + c]
                      : (W[(size_t)(o - O) * 2 * C + C + c] -
                         W[(size_t)(o - O) * 2 * C + c]);
  _Float16 hv = (_Float16)val;
  Wph[t] = hv;
  Wpl[t] = (_Float16)(val - (float)hv);
}

// ---------------------------------------------------------------- layer-1 uv (K=3, fp32)
__global__ void gemm_uv3_kernel(const float* __restrict__ x,
                                const float* __restrict__ Wp,
                                float* __restrict__ out) {
  int t = blockIdx.x * 256 + threadIdx.x;
  if (t >= BATCH * N_PTS * 128) return;
  int n = t >> 7, o = t & 127;
  const float* xr = x + (size_t)n * 3;
  const float* wr = Wp + (size_t)o * 3;
  out[t] = xr[0] * wr[0] + xr[1] * wr[1] + xr[2] * wr[2];
}

// ---------------------------------------------------------------- edge gather+max
template<int O>
__global__ void edge_max_kernel(const float* __restrict__ uv,
                                const int* __restrict__ knn_idx,
                                const float* __restrict__ gamma,
                                const float* __restrict__ beta,
                                float* __restrict__ out, int out_stride) {
  constexpr int P = 256 / O;
  int tid = threadIdx.x;
  int p = tid / O, o = tid % O;
  int n = blockIdx.x * P + p;
  int b = n / N_PTS;
  float v = uv[(size_t)n * (2 * O) + O + o];
  float g = gamma[o], be = beta[o];
  const int* ir = knn_idx + (size_t)n * KNN_K;
  int mk[KNN_K];
#pragma unroll
  for (int k = 0; k < KNN_K; ++k) mk[k] = ir[k];
  float mx = -FLT_MAX;
#pragma unroll
  for (int k = 0; k < KNN_K; ++k) {
    float u = uv[(size_t)(b * N_PTS + mk[k]) * (2 * O) + o];
    float y = g * ((u + v) * BN_SCALE_F) + be;
    y = (y > 0.f) ? y : 0.2f * y;
    mx = fmaxf(mx, y);
  }
  out[(size_t)n * out_stride + o] = mx;
}

// ---------------------------------------------------------------- head: pool partials -> gvec
__global__ void pool_kernel(const float* __restrict__ pmax,
                            const float* __restrict__ psum,
                            float* __restrict__ gvec) {
  int t = blockIdx.x * 256 + threadIdx.x;   // 8192 threads
  int b = t >> 10, o = t & 1023;
  float mx = -FLT_MAX, sm = 0.f;
#pragma unroll
  for (int ch = 0; ch < 16; ++ch) {
    size_t idx = (size_t)(b * 16 + ch) * 1024 + o;
    mx = fmaxf(mx, pmax[idx]);
    sm += psum[idx];
  }
  gvec[b * 2048 + o] = mx;
  gvec[b * 2048 + 1024 + o] = sm * (1.f / 2048.f);
}

// ---------------------------------------------------------------- head: fc1
__global__ void fc1_kernel(const float* __restrict__ gvec,
                           const float* __restrict__ L1,
                           const float* __restrict__ g6, const float* __restrict__ b6,
                           float* __restrict__ h1) {
  int o = blockIdx.x * 4 + (threadIdx.x >> 6);   // 0..511
  int lane = threadIdx.x & 63;
  float4 w[8];
#pragma unroll
  for (int i = 0; i < 8; ++i)
    w[i] = *(const float4*)&L1[(size_t)o * 2048 + i * 256 + lane * 4];
  float g = g6[o], be = b6[o];
  for (int b = 0; b < BATCH; ++b) {
    float s = 0.f;
#pragma unroll
    for (int i = 0; i < 8; ++i) {
      float4 v = *(const float4*)&gvec[b * 2048 + i * 256 + lane * 4];
      s += w[i].x * v.x + w[i].y * v.y + w[i].z * v.z + w[i].w * v.w;
    }
#pragma unroll
    for (int off = 32; off > 0; off >>= 1) s += __shfl_down(s, off);
    if (lane == 0) {
      float y = g * (s * BN_SCALE_F) + be;
      h1[b * 512 + o] = (y > 0.f) ? y : 0.2f * y;
    }
  }
}

// ---------------------------------------------------------------- head: fc2
__global__ void fc2_kernel(const float* __restrict__ h1,
                           const float* __restrict__ L2, const float* __restrict__ L2b,
                           const float* __restrict__ g7, const float* __restrict__ b7,
                           float* __restrict__ h2) {
  int w = blockIdx.x * 4 + (threadIdx.x >> 6);   // 0..2047
  int lane = threadIdx.x & 63;
  int b = w >> 8, o = w & 255;
  float s = 0.f;
#pragma unroll
  for (int i = 0; i < 2; ++i) {
    float4 wv = *(const float4*)&L2[(size_t)o * 512 + i * 256 + lane * 4];
    float4 hv = *(const float4*)&h1[b * 512 + i * 256 + lane * 4];
    s += wv.x * hv.x + wv.y * hv.y + wv.z * hv.z + wv.w * hv.w;
  }
#pragma unroll
  for (int off = 32; off > 0; off >>= 1) s += __shfl_down(s, off);
  if (lane == 0) {
    float y = g7[o] * ((s + L2b[o]) * BN_SCALE_F) + b7[o];
    h2[b * 256 + o] = (y > 0.f) ? y : 0.2f * y;
  }
}

// ---------------------------------------------------------------- head: fc3
__global__ void fc3_kernel(const float* __restrict__ h2,
                           const float* __restrict__ L3, const float* __restrict__ L3b,
                           float* __restrict__ out) {
  int w = blockIdx.x * 4 + (threadIdx.x >> 6);   // 0..79
  int lane = threadIdx.x & 63;
  int b = w / 10, o = w - b * 10;
  float4 wv = *(const float4*)&L3[(size_t)o * 256 + lane * 4];
  float4 hv = *(const float4*)&h2[b * 256 + lane * 4];
  float s = wv.x * hv.x + wv.y * hv.y + wv.z * hv.z + wv.w * hv.w;
#pragma unroll
  for (int off = 32; off > 0; off >>= 1) s += __shfl_down(s, off);
  if (lane == 0) out[b * 10 + o] = s + L3b[o];
}

// ---------------------------------------------------------------- launch
extern "C" void kernel_launch(void* const* d_in, const int* in_sizes, int n_in,
                              void* d_out, int out_size, void* d_ws, size_t ws_size,
                              hipStream_t stream) {
  const float* x   = (const float*)d_in[0];
  const float* W1  = (const float*)d_in[1];
  const float* g1  = (const float*)d_in[2];
  const float* b1  = (const float*)d_in[3];
  const float* W2  = (const float*)d_in[4];
  const float* g2  = (const float*)d_in[5];
  const float* b2  = (const float*)d_in[6];
  const float* W3  = (const float*)d_in[7];
  const float* g3  = (const float*)d_in[8];
  const float* b3  = (const float*)d_in[9];
  const float* W4  = (const float*)d_in[10];
  const float* g4  = (const float*)d_in[11];
  const float* b4  = (const float*)d_in[12];
  const float* W5  = (const float*)d_in[13];
  const float* g5  = (const float*)d_in[14];
  const float* b5  = (const float*)d_in[15];
  const float* L1  = (const float*)d_in[16];
  const float* g6  = (const float*)d_in[17];
  const float* b6  = (const float*)d_in[18];
  const float* L2  = (const float*)d_in[19];
  const float* L2b = (const float*)d_in[20];
  const float* g7  = (const float*)d_in[21];
  const float* b7  = (const float*)d_in[22];
  const float* L3  = (const float*)d_in[23];
  const float* L3b = (const float*)d_in[24];
  float* out = (float*)d_out;

  // ---- workspace layout (bytes)
  char* p = (char*)d_ws;
  float* xc = (float*)p;          p += (size_t)16384 * 512 * 4;   // 33.55 MB
  float* xx = (float*)p;          p += 16384 * 4;
  int*   idx = (int*)p;           p += (size_t)16384 * KNN_K * 4; // 1.31 MB
  float* wp = (float*)p;          p += 2 * 64 * 3 * 4 + 64;       // layer1 fp32 W'
  _Float16* wph = (_Float16*)p;   p += (size_t)512 * 128 * 2;
  _Float16* wpl = (_Float16*)p;   p += (size_t)512 * 128 * 2;
  _Float16* Xh = (_Float16*)p;    p += (size_t)16384 * 128 * 2;   // 4.19 MB
  _Float16* Xl = (_Float16*)p;    p += (size_t)16384 * 128 * 2;
  float* gvec = (float*)p;        p += BATCH * 2048 * 4;          // 64 KB
  float* h1g  = (float*)p;        p += BATCH * 512 * 4;
  float* h2g  = (float*)p;        p += BATCH * 256 * 4;
  char* region = p;
  size_t baseB = (size_t)(region - (char*)d_ws);

  // region users: D (NB*16.78MB) | uv (33.55MB) | xch+w5h+pools (18.9MB)
  const size_t dB1 = (size_t)N_PTS * N_PTS * 4;
  const size_t uvB = (size_t)16384 * 512 * 4;
  int NB = 1;
  for (int cand = 8; cand >= 1; cand >>= 1) {
    size_t need = (size_t)cand * dB1 > uvB ? (size_t)cand * dB1 : uvB;
    if (baseB + need <= ws_size) { NB = cand; break; }
  }

  float* D  = (float*)region;
  float* uv = (float*)region;
  _Float16* xch = (_Float16*)region;
  _Float16* w5h = xch + (size_t)16384 * 512;
  float* pmax = (float*)(w5h + (size_t)1024 * 512);
  float* psum = pmax + (size_t)BATCH * 16 * 1024;

  const int NPTS_TOT = BATCH * N_PTS;            // 16384

  // ================= layer 1: x (C=3) -> xc[:, 0:64]
  sqnorm_kernel<<<(NPTS_TOT + 255) / 256, 256, 0, stream>>>(x, 3, 3, xx);
  for (int b0 = 0; b0 < BATCH; b0 += NB) {
    dist3_kernel<<<NB * 1024, 256, 0, stream>>>(x, xx, b0, D);
    topk_kernel<<<NB * N_PTS / 4, 256, 0, stream>>>(D, b0, idx);
  }
  prep_wp3_kernel<<<2, 256, 0, stream>>>(W1, wp, 64, 3);
  gemm_uv3_kernel<<<(NPTS_TOT * 128 + 255) / 256, 256, 0, stream>>>(x, wp, uv);
  edge_max_kernel<64><<<NPTS_TOT / 4, 256, 0, stream>>>(uv, idx, g1, b1, xc + 0, XC_CH);

  // ================= layer 2: x1 (C=64) -> xc[:, 64:128]
  split_sq_kernel<64><<<NPTS_TOT * 16 / 256, 256, 0, stream>>>(xc + 0, XC_CH, Xh, Xl, xx);
  for (int b0 = 0; b0 < BATCH; b0 += NB) {
    dist_mfma_kernel<64><<<NB * 256, 256, 0, stream>>>(Xh, Xl, xx, b0, D);
    topk_kernel<<<NB * N_PTS / 4, 256, 0, stream>>>(D, b0, idx);
  }
  prep_wpf16_kernel<<<(2 * 64 * 64 + 255) / 256, 256, 0, stream>>>(W2, wph, wpl, 64, 64);
  uv_mfma_kernel<64><<<1 * 128, 256, 0, stream>>>(Xh, Xl, wph, wpl, uv, 128);
  edge_max_kernel<64><<<NPTS_TOT / 4, 256, 0, stream>>>(uv, idx, g2, b2, xc + 64, XC_CH);

  // ================= layer 3: x2 (C=64) -> xc[:, 128:256]
  split_sq_kernel<64><<<NPTS_TOT * 16 / 256, 256, 0, stream>>>(xc + 64, XC_CH, Xh, Xl, xx);
  for (int b0 = 0; b0 < BATCH; b0 += NB) {
    dist_mfma_kernel<64><<<NB * 256, 256, 0, stream>>>(Xh, Xl, xx, b0, D);
    topk_kernel<<<NB * N_PTS / 4, 256, 0, stream>>>(D, b0, idx);
  }
  prep_wpf16_kernel<<<(2 * 128 * 64 + 255) / 256, 256, 0, stream>>>(W3, wph, wpl, 128, 64);
  uv_mfma_kernel<64><<<2 * 128, 256, 0, stream>>>(Xh, Xl, wph, wpl, uv, 256);
  edge_max_kernel<128><<<NPTS_TOT / 2, 256, 0, stream>>>(uv, idx, g3, b3, xc + 128, XC_CH);

  // ================= layer 4: x3 (C=128) -> xc[:, 256:512]
  split_sq_kernel<128><<<NPTS_TOT * 32 / 256, 256, 0, stream>>>(xc + 128, XC_CH, Xh, Xl, xx);
  for (int b0 = 0; b0 < BATCH; b0 += NB) {
    dist_mfma_kernel<128><<<NB * 256, 256, 0, stream>>>(Xh, Xl, xx, b0, D);
    topk_kernel<<<NB * N_PTS / 4, 256, 0, stream>>>(D, b0, idx);
  }
  prep_wpf16_kernel<<<(2 * 256 * 128 + 255) / 256, 256, 0, stream>>>(W4, wph, wpl, 256, 128);
  uv_mfma_kernel<128><<<4 * 128, 256, 0, stream>>>(Xh, Xl, wph, wpl, uv, 512);
  edge_max_kernel<256><<<NPTS_TOT, 256, 0, stream>>>(uv, idx, g4, b4, xc + 256, XC_CH);

  // ================= W5 (f16 MFMA) + pooling, GEMV head
  cvt_f16_kernel<<<(16384 * 512 / 4 + 255) / 256, 256, 0, stream>>>(xc, xch, 16384 * 512 / 4);
  cvt_f16_kernel<<<(1024 * 512 / 4 + 255) / 256, 256, 0, stream>>>(W5, w5h, 1024 * 512 / 4);
  w5_mfma_kernel<<<128 * 8, 256, 0, stream>>>(xch, w5h, g5, b5, pmax, psum);
  pool_kernel<<<32, 256, 0, stream>>>(pmax, psum, gvec);
  fc1_kernel<<<128, 256, 0, stream>>>(gvec, L1, g6, b6, h1g);
  fc2_kernel<<<512, 256, 0, stream>>>(h1g, L2, L2b, g7, b7, h2g);
  fc3_kernel<<<20, 256, 0, stream>>>(h2g, L3, L3b, out);
}